// Round 1
// baseline (844.030 us; speedup 1.0000x reference)
//
#include <hip/hip_runtime.h>
#include <math.h>

#define D 128      // hidden / input dim
#define DO 64      // output dim

// ---------------- degree + norm ----------------
__global__ void k_degree(const int* __restrict__ src, const int* __restrict__ dst,
                         int* __restrict__ dego, int* __restrict__ degi, int E) {
    int i = blockIdx.x * 256 + threadIdx.x;
    if (i < E) {
        atomicAdd(&dego[src[i]], 1);
        atomicAdd(&degi[dst[i]], 1);
    }
}

__global__ void k_norms(const int* __restrict__ dego, const int* __restrict__ degi,
                        float* __restrict__ ns, float* __restrict__ nd, int N) {
    int i = blockIdx.x * 256 + threadIdx.x;
    if (i < N) {
        int a = dego[i]; if (a < 1) a = 1;
        int b = degi[i]; if (b < 1) b = 1;
        ns[i] = rsqrtf((float)a);
        nd[i] = rsqrtf((float)b);
    }
}

// ---------------- exclusive scan (3 kernels) ----------------
__global__ void k_scan_block(const int* __restrict__ cnt, int* __restrict__ rp,
                             int* __restrict__ bsum, int N) {
    __shared__ int sdat[256];
    int i = blockIdx.x * 256 + threadIdx.x;
    int v = (i < N) ? cnt[i] : 0;
    sdat[threadIdx.x] = v;
    __syncthreads();
    for (int off = 1; off < 256; off <<= 1) {
        int t = (threadIdx.x >= off) ? sdat[threadIdx.x - off] : 0;
        __syncthreads();
        sdat[threadIdx.x] += t;
        __syncthreads();
    }
    if (i < N) rp[i] = sdat[threadIdx.x] - v;   // exclusive
    if (threadIdx.x == 255) bsum[blockIdx.x] = sdat[255];
}

__global__ void k_scan_bsum(int* __restrict__ bsum, int NB) {
    __shared__ int sdat[512];
    int tid = threadIdx.x;
    int v = (tid < NB) ? bsum[tid] : 0;
    sdat[tid] = v;
    __syncthreads();
    for (int off = 1; off < 512; off <<= 1) {
        int t = (tid >= off) ? sdat[tid - off] : 0;
        __syncthreads();
        sdat[tid] += t;
        __syncthreads();
    }
    if (tid < NB) bsum[tid] = sdat[tid] - v;    // exclusive
}

__global__ void k_scan_add(int* __restrict__ rp, const int* __restrict__ bsum,
                           int N, int E) {
    int i = blockIdx.x * 256 + threadIdx.x;
    if (i < N) rp[i] += bsum[i >> 8];
    if (i == N) rp[N] = E;
}

// ---------------- CSR fill (dst-sorted edge list) ----------------
__global__ void k_csr_fill(const int* __restrict__ src, const int* __restrict__ dst,
                           const int* __restrict__ rp, int* __restrict__ fill,
                           int* __restrict__ col, int E) {
    int i = blockIdx.x * 256 + threadIdx.x;
    if (i < E) {
        int d = dst[i];
        int p = rp[d] + atomicAdd(&fill[d], 1);
        col[p] = src[i];
    }
}

// ---------------- input scale: A = features * norm_src ----------------
__global__ void k_scale0(const float* __restrict__ F, const float* __restrict__ ns,
                         float* __restrict__ A, int N) {
    int i = blockIdx.x * 256 + threadIdx.x;   // over N*32 float4
    if (i < N * 32) {
        int n = i >> 5;
        float s = ns[n];
        float4 v = ((const float4*)F)[i];
        v.x *= s; v.y *= s; v.z *= s; v.w *= s;
        ((float4*)A)[i] = v;
    }
}

// ---------------- SpMM (D=128): out[r] = norm_dst[r] * sum A[col] ----------------
__global__ __launch_bounds__(256) void k_spmm128(
    const float* __restrict__ A, const int* __restrict__ rp,
    const int* __restrict__ col, const float* __restrict__ nd,
    float* __restrict__ out, int N) {
    int row = blockIdx.x * 8 + (threadIdx.x >> 5);
    if (row >= N) return;
    int lane = threadIdx.x & 31;
    int s = rp[row], e = rp[row + 1];
    const float4* A4 = (const float4*)A;
    float4 a0 = make_float4(0.f, 0.f, 0.f, 0.f);
    float4 a1 = make_float4(0.f, 0.f, 0.f, 0.f);
    int i = s;
    for (; i + 1 < e; i += 2) {
        int c0 = col[i], c1 = col[i + 1];
        float4 v0 = A4[(size_t)c0 * 32 + lane];
        float4 v1 = A4[(size_t)c1 * 32 + lane];
        a0.x += v0.x; a0.y += v0.y; a0.z += v0.z; a0.w += v0.w;
        a1.x += v1.x; a1.y += v1.y; a1.z += v1.z; a1.w += v1.w;
    }
    if (i < e) {
        int c = col[i];
        float4 v = A4[(size_t)c * 32 + lane];
        a0.x += v.x; a0.y += v.y; a0.z += v.z; a0.w += v.w;
    }
    float sc = nd[row];
    float4 r;
    r.x = (a0.x + a1.x) * sc; r.y = (a0.y + a1.y) * sc;
    r.z = (a0.z + a1.z) * sc; r.w = (a0.w + a1.w) * sc;
    ((float4*)out)[(size_t)row * 32 + lane] = r;
}

// ---------------- GEMM: out[N,J] = M[N,128] @ W[128,J]; optional epilogue ----------------
// EPI=true: out = relu(acc + bias) * ns[n];  EPI=false: out = acc
template <int J, bool EPI>
__global__ __launch_bounds__(256) void k_gemm(
    const float* __restrict__ M, const float* __restrict__ W,
    const float* __restrict__ bias, const float* __restrict__ ns,
    float* __restrict__ out, int N) {
    __shared__ float Mt[128][65];   // transposed tile, stride 65 -> conflict-lite
    const int tid = threadIdx.x;
    const int n0 = blockIdx.x * 64;
    const int jb = blockIdx.y * 64;

    const float4* M4 = (const float4*)M;
#pragma unroll
    for (int it = 0; it < 8; ++it) {
        int id = it * 256 + tid;
        int nl = id >> 5;       // 0..63
        int k4 = id & 31;       // 0..31
        float4 v = make_float4(0.f, 0.f, 0.f, 0.f);
        int n = n0 + nl;
        if (n < N) v = M4[(size_t)n * 32 + k4];
        Mt[k4 * 4 + 0][nl] = v.x;
        Mt[k4 * 4 + 1][nl] = v.y;
        Mt[k4 * 4 + 2][nl] = v.z;
        Mt[k4 * 4 + 3][nl] = v.w;
    }
    __syncthreads();

    const int tx = tid & 15;
    const int ty = tid >> 4;
    float acc[4][4] = {};
    const float4* W4 = (const float4*)W;
#pragma unroll 8
    for (int k = 0; k < 128; ++k) {
        float4 wv = W4[k * (J / 4) + (jb >> 2) + tx];
        float m0 = Mt[k][ty * 4 + 0];
        float m1 = Mt[k][ty * 4 + 1];
        float m2 = Mt[k][ty * 4 + 2];
        float m3 = Mt[k][ty * 4 + 3];
        acc[0][0] += m0 * wv.x; acc[0][1] += m0 * wv.y; acc[0][2] += m0 * wv.z; acc[0][3] += m0 * wv.w;
        acc[1][0] += m1 * wv.x; acc[1][1] += m1 * wv.y; acc[1][2] += m1 * wv.z; acc[1][3] += m1 * wv.w;
        acc[2][0] += m2 * wv.x; acc[2][1] += m2 * wv.y; acc[2][2] += m2 * wv.z; acc[2][3] += m2 * wv.w;
        acc[3][0] += m3 * wv.x; acc[3][1] += m3 * wv.y; acc[3][2] += m3 * wv.z; acc[3][3] += m3 * wv.w;
    }

#pragma unroll
    for (int i = 0; i < 4; ++i) {
        int n = n0 + ty * 4 + i;
        if (n >= N) continue;
        float4 r = make_float4(acc[i][0], acc[i][1], acc[i][2], acc[i][3]);
        if (EPI) {
            float sc = ns[n];
            float4 bv = ((const float4*)bias)[(jb >> 2) + tx];
            r.x = fmaxf(r.x + bv.x, 0.f) * sc;
            r.y = fmaxf(r.y + bv.y, 0.f) * sc;
            r.z = fmaxf(r.z + bv.z, 0.f) * sc;
            r.w = fmaxf(r.w + bv.w, 0.f) * sc;
        }
        ((float4*)out)[(size_t)n * (J / 4) + (jb >> 2) + tx] = r;
    }
}

// ---------------- layer-3 aggregate (64-dim) + bias + log_softmax ----------------
__global__ __launch_bounds__(256) void k_agg64_lsm(
    const float* __restrict__ Y, const int* __restrict__ rp,
    const int* __restrict__ col, const float* __restrict__ nd,
    const float* __restrict__ b3, float* __restrict__ out, int N) {
    int row = blockIdx.x * 4 + (threadIdx.x >> 6);
    if (row >= N) return;
    int lane = threadIdx.x & 63;
    int s = rp[row], e = rp[row + 1];
    float a0 = 0.f, a1 = 0.f;
    int i = s;
    for (; i + 1 < e; i += 2) {
        a0 += Y[(size_t)col[i] * 64 + lane];
        a1 += Y[(size_t)col[i + 1] * 64 + lane];
    }
    if (i < e) a0 += Y[(size_t)col[i] * 64 + lane];
    float v = (a0 + a1) * nd[row] + b3[lane];
    float m = v;
#pragma unroll
    for (int o = 32; o; o >>= 1) m = fmaxf(m, __shfl_xor(m, o));
    float ex = expf(v - m);
    float sum = ex;
#pragma unroll
    for (int o = 32; o; o >>= 1) sum += __shfl_xor(sum, o);
    out[(size_t)row * 64 + lane] = v - m - logf(sum);
}

// ---------------- launch ----------------
extern "C" void kernel_launch(void* const* d_in, const int* in_sizes, int n_in,
                              void* d_out, int out_size, void* d_ws, size_t ws_size,
                              hipStream_t stream) {
    const float* features = (const float*)d_in[0];
    const int*   src      = (const int*)d_in[1];
    const int*   dst      = (const int*)d_in[2];
    const float* W1       = (const float*)d_in[3];
    const float* b1       = (const float*)d_in[4];
    const float* W2       = (const float*)d_in[5];
    const float* b2       = (const float*)d_in[6];
    const float* W3       = (const float*)d_in[7];
    const float* b3       = (const float*)d_in[8];
    float* out = (float*)d_out;

    const int N = in_sizes[0] / D;   // 100000
    const int E = in_sizes[1];       // 1600000

    char* p = (char*)d_ws;
    float* A  = (float*)p; p += (size_t)N * D * sizeof(float);
    float* B  = (float*)p; p += (size_t)N * D * sizeof(float);
    int* col  = (int*)p;   p += (size_t)E * sizeof(int);
    int* rp   = (int*)p;   p += ((size_t)N + 4) * sizeof(int);
    // contiguous zero-init region: fill, dego, degi
    int* fill = (int*)p;   p += (size_t)N * sizeof(int);
    int* dego = (int*)p;   p += (size_t)N * sizeof(int);
    int* degi = (int*)p;   p += (size_t)N * sizeof(int);
    float* ns = (float*)p; p += (size_t)N * sizeof(float);
    float* nd = (float*)p; p += (size_t)N * sizeof(float);
    int* bsum = (int*)p;   p += 4096 * sizeof(int);

    hipMemsetAsync(fill, 0, (size_t)3 * N * sizeof(int), stream);

    const int gE = (E + 255) / 256;
    const int gN = (N + 255) / 256;   // also NB for bsum scan (391 <= 512)

    k_degree<<<gE, 256, 0, stream>>>(src, dst, dego, degi, E);
    k_norms<<<gN, 256, 0, stream>>>(dego, degi, ns, nd, N);
    k_scan_block<<<gN, 256, 0, stream>>>(degi, rp, bsum, N);
    k_scan_bsum<<<1, 512, 0, stream>>>(bsum, gN);
    k_scan_add<<<(N + 1 + 255) / 256, 256, 0, stream>>>(rp, bsum, N, E);
    k_csr_fill<<<gE, 256, 0, stream>>>(src, dst, rp, fill, col, E);

    // layer 1
    k_scale0<<<(N * 32 + 255) / 256, 256, 0, stream>>>(features, ns, A, N);
    k_spmm128<<<(N + 7) / 8, 256, 0, stream>>>(A, rp, col, nd, B, N);
    dim3 g1((N + 63) / 64, 2);
    k_gemm<128, true><<<g1, 256, 0, stream>>>(B, W1, b1, ns, A, N);

    // layer 2
    k_spmm128<<<(N + 7) / 8, 256, 0, stream>>>(A, rp, col, nd, B, N);
    k_gemm<128, true><<<g1, 256, 0, stream>>>(B, W2, b2, ns, A, N);

    // layer 3: transform first (64-dim aggregate), then fused agg+bias+log_softmax
    dim3 g3((N + 63) / 64, 1);
    k_gemm<64, false><<<g3, 256, 0, stream>>>(A, W3, nullptr, nullptr, B, N);
    k_agg64_lsm<<<(N + 3) / 4, 256, 0, stream>>>(B, rp, col, nd, b3, out, N);
}

// Round 2
// 796.906 us; speedup vs baseline: 1.0591x; 1.0591x over previous
//
#include <hip/hip_runtime.h>
#include <math.h>

#define D 128      // hidden / input dim
#define DO 64      // output dim

// ======================= shared GEMM body =======================
// out[N,J] = M[N,128] @ W[128,J], 64xJ-tile per (nblk,jblk), 256 threads.
// LDS: natural-layout M tile [64][132] (pad 4 floats): b128 staging writes
// (conflict-lite), hot-loop b32 reads are broadcast across tx (conflict-free).
template <int J>
__device__ __forceinline__ void gemm_body(
    const float* __restrict__ M, const float* __restrict__ W,
    float* __restrict__ out, int N, int nblk, int jblk, float* smem) {
    float (*Ms)[132] = (float (*)[132])smem;
    const int tid = threadIdx.x;
    const int n0 = nblk * 64;
    const int jb = jblk * 64;

    const float4* M4 = (const float4*)M;
#pragma unroll
    for (int it = 0; it < 8; ++it) {
        int id = it * 256 + tid;
        int nl = id >> 5;       // 0..63
        int k4 = id & 31;       // 0..31
        float4 v = make_float4(0.f, 0.f, 0.f, 0.f);
        int n = n0 + nl;
        if (n < N) v = M4[(size_t)n * 32 + k4];
        *(float4*)&Ms[nl][k4 * 4] = v;   // 528B rows -> 16B aligned
    }
    __syncthreads();

    const int tx = tid & 15;
    const int ty = tid >> 4;
    float acc[4][4] = {};
    const float4* W4 = (const float4*)W;
#pragma unroll 4
    for (int k = 0; k < 128; ++k) {
        float4 wv = W4[(size_t)k * (J / 4) + (jb >> 2) + tx];
#pragma unroll
        for (int i = 0; i < 4; ++i) {
            float m = Ms[ty * 4 + i][k];
            acc[i][0] += m * wv.x; acc[i][1] += m * wv.y;
            acc[i][2] += m * wv.z; acc[i][3] += m * wv.w;
        }
    }

#pragma unroll
    for (int i = 0; i < 4; ++i) {
        int n = n0 + ty * 4 + i;
        if (n < N)
            ((float4*)out)[(size_t)n * (J / 4) + (jb >> 2) + tx] =
                make_float4(acc[i][0], acc[i][1], acc[i][2], acc[i][3]);
    }
}

// ======================= fused: degree histogram + T1 = F @ W1 =======================
// Degree blocks are fabric-atomic-bound (VALU ~0%), GEMM blocks are VALU-bound;
// interleaved 1:(S-1) so both pipes run concurrently on every CU.
__global__ __launch_bounds__(256) void k_deg_gemm1(
    const int* __restrict__ src, const int* __restrict__ dst, int E,
    int NBd, int S,
    int* __restrict__ dego, int* __restrict__ degi,
    const float* __restrict__ F, const float* __restrict__ W1,
    float* __restrict__ T1, int N) {
    __shared__ float smem[64 * 132];
    const int bid = blockIdx.x;
    const int did = bid / S;
    const bool isdeg = (bid % S == 0) && (did < NBd);
    if (isdeg) {
        const int nE4 = E >> 2;
        int idx = did * 256 + threadIdx.x;
        if (idx < nE4) {
            int4 s4 = ((const int4*)src)[idx];
            int4 d4 = ((const int4*)dst)[idx];
            atomicAdd(&dego[s4.x], 1); atomicAdd(&dego[s4.y], 1);
            atomicAdd(&dego[s4.z], 1); atomicAdd(&dego[s4.w], 1);
            atomicAdd(&degi[d4.x], 1); atomicAdd(&degi[d4.y], 1);
            atomicAdd(&degi[d4.z], 1); atomicAdd(&degi[d4.w], 1);
        }
        if (idx == 0) {             // tail (E not divisible by 4)
            for (int i = nE4 * 4; i < E; ++i) {
                atomicAdd(&dego[src[i]], 1);
                atomicAdd(&degi[dst[i]], 1);
            }
        }
        return;
    }
    int ndeg_before = min(bid / S + 1, NBd);
    int gid = bid - ndeg_before;
    gemm_body<128>(F, W1, T1, N, gid >> 1, gid & 1, smem);
}

// ======================= standalone GEMM =======================
template <int J>
__global__ __launch_bounds__(256) void k_gemm(
    const float* __restrict__ M, const float* __restrict__ W,
    float* __restrict__ out, int N) {
    __shared__ float smem[64 * 132];
    gemm_body<J>(M, W, out, N, blockIdx.x, blockIdx.y, smem);
}

// ======================= exclusive scan (3 kernels) =======================
__global__ void k_scan_block(const int* __restrict__ cnt, int* __restrict__ rp,
                             int* __restrict__ bsum, int N) {
    __shared__ int sdat[256];
    int i = blockIdx.x * 256 + threadIdx.x;
    int v = (i < N) ? cnt[i] : 0;
    sdat[threadIdx.x] = v;
    __syncthreads();
    for (int off = 1; off < 256; off <<= 1) {
        int t = (threadIdx.x >= off) ? sdat[threadIdx.x - off] : 0;
        __syncthreads();
        sdat[threadIdx.x] += t;
        __syncthreads();
    }
    if (i < N) rp[i] = sdat[threadIdx.x] - v;   // exclusive
    if (threadIdx.x == 255) bsum[blockIdx.x] = sdat[255];
}

__global__ void k_scan_bsum(int* __restrict__ bsum, int NB) {
    __shared__ int sdat[512];
    int tid = threadIdx.x;
    int v = (tid < NB) ? bsum[tid] : 0;
    sdat[tid] = v;
    __syncthreads();
    for (int off = 1; off < 512; off <<= 1) {
        int t = (tid >= off) ? sdat[tid - off] : 0;
        __syncthreads();
        sdat[tid] += t;
        __syncthreads();
    }
    if (tid < NB) bsum[tid] = sdat[tid] - v;    // exclusive
}

// rp finalize + seed fill=rp (saves a random rp[] read per edge in csr_fill)
// + node norms, one pass.
__global__ void k_scan_add_norms(int* __restrict__ rp, const int* __restrict__ bsum,
                                 int* __restrict__ fill,
                                 const int* __restrict__ dego, const int* __restrict__ degi,
                                 float* __restrict__ ns, float* __restrict__ nd,
                                 int N, int E) {
    int i = blockIdx.x * 256 + threadIdx.x;
    if (i < N) {
        int r = rp[i] + bsum[i >> 8];
        rp[i] = r;
        fill[i] = r;
        int a = dego[i]; if (a < 1) a = 1;
        int b = degi[i]; if (b < 1) b = 1;
        ns[i] = rsqrtf((float)a);
        nd[i] = rsqrtf((float)b);
    }
    if (i == N) rp[N] = E;
}

// ======================= CSR fill (dst-sorted edge list) =======================
__global__ void k_csr_fill(const int* __restrict__ src, const int* __restrict__ dst,
                           int* __restrict__ fill, int* __restrict__ col, int E) {
    const int nE4 = E >> 2;
    int idx = blockIdx.x * 256 + threadIdx.x;
    if (idx < nE4) {
        int4 s4 = ((const int4*)src)[idx];
        int4 d4 = ((const int4*)dst)[idx];
        col[atomicAdd(&fill[d4.x], 1)] = s4.x;
        col[atomicAdd(&fill[d4.y], 1)] = s4.y;
        col[atomicAdd(&fill[d4.z], 1)] = s4.z;
        col[atomicAdd(&fill[d4.w], 1)] = s4.w;
    }
    if (idx == 0) {
        for (int i = nE4 * 4; i < E; ++i)
            col[atomicAdd(&fill[dst[i]], 1)] = src[i];
    }
}

// ======================= SpMM (D=128), transform-first =======================
// out[r] = EPI ? relu(nd[r]*sum + b)*ns[r] : nd[r]*sum
// SCALE_SRC (layer 1): sum = sum_c ns[c]*T[c]  (fma, free vs add)
template <bool SCALE_SRC, bool EPI>
__global__ __launch_bounds__(256) void k_spmm(
    const float* __restrict__ A, const int* __restrict__ rp,
    const int* __restrict__ col, const float* __restrict__ ns,
    const float* __restrict__ nd, const float* __restrict__ bias,
    float* __restrict__ out, int N) {
    int row = blockIdx.x * 8 + (threadIdx.x >> 5);
    if (row >= N) return;
    int lane = threadIdx.x & 31;
    int s = rp[row], e = rp[row + 1];
    const float4* A4 = (const float4*)A;
    float4 a0 = make_float4(0.f,0.f,0.f,0.f), a1 = a0, a2 = a0, a3 = a0;
    int i = s;
    for (; i + 3 < e; i += 4) {
        int c0 = col[i], c1 = col[i+1], c2 = col[i+2], c3 = col[i+3];
        float4 v0 = A4[(size_t)c0 * 32 + lane];
        float4 v1 = A4[(size_t)c1 * 32 + lane];
        float4 v2 = A4[(size_t)c2 * 32 + lane];
        float4 v3 = A4[(size_t)c3 * 32 + lane];
        if (SCALE_SRC) {
            float s0 = ns[c0], s1 = ns[c1], s2 = ns[c2], s3 = ns[c3];
            a0.x = fmaf(v0.x,s0,a0.x); a0.y = fmaf(v0.y,s0,a0.y); a0.z = fmaf(v0.z,s0,a0.z); a0.w = fmaf(v0.w,s0,a0.w);
            a1.x = fmaf(v1.x,s1,a1.x); a1.y = fmaf(v1.y,s1,a1.y); a1.z = fmaf(v1.z,s1,a1.z); a1.w = fmaf(v1.w,s1,a1.w);
            a2.x = fmaf(v2.x,s2,a2.x); a2.y = fmaf(v2.y,s2,a2.y); a2.z = fmaf(v2.z,s2,a2.z); a2.w = fmaf(v2.w,s2,a2.w);
            a3.x = fmaf(v3.x,s3,a3.x); a3.y = fmaf(v3.y,s3,a3.y); a3.z = fmaf(v3.z,s3,a3.z); a3.w = fmaf(v3.w,s3,a3.w);
        } else {
            a0.x += v0.x; a0.y += v0.y; a0.z += v0.z; a0.w += v0.w;
            a1.x += v1.x; a1.y += v1.y; a1.z += v1.z; a1.w += v1.w;
            a2.x += v2.x; a2.y += v2.y; a2.z += v2.z; a2.w += v2.w;
            a3.x += v3.x; a3.y += v3.y; a3.z += v3.z; a3.w += v3.w;
        }
    }
    for (; i < e; ++i) {
        int c = col[i];
        float4 v = A4[(size_t)c * 32 + lane];
        float sc = SCALE_SRC ? ns[c] : 1.0f;
        a0.x = fmaf(v.x,sc,a0.x); a0.y = fmaf(v.y,sc,a0.y);
        a0.z = fmaf(v.z,sc,a0.z); a0.w = fmaf(v.w,sc,a0.w);
    }
    float4 t;
    t.x = (a0.x+a1.x) + (a2.x+a3.x);
    t.y = (a0.y+a1.y) + (a2.y+a3.y);
    t.z = (a0.z+a1.z) + (a2.z+a3.z);
    t.w = (a0.w+a1.w) + (a2.w+a3.w);
    float sd = nd[row];
    if (EPI) {
        float sr = ns[row];
        float4 bv = ((const float4*)bias)[lane];
        t.x = fmaxf(fmaf(t.x, sd, bv.x), 0.f) * sr;
        t.y = fmaxf(fmaf(t.y, sd, bv.y), 0.f) * sr;
        t.z = fmaxf(fmaf(t.z, sd, bv.z), 0.f) * sr;
        t.w = fmaxf(fmaf(t.w, sd, bv.w), 0.f) * sr;
    } else {
        t.x *= sd; t.y *= sd; t.z *= sd; t.w *= sd;
    }
    ((float4*)out)[(size_t)row * 32 + lane] = t;
}

// ======================= layer-3 aggregate (64-dim) + bias + log_softmax =======================
__global__ __launch_bounds__(256) void k_agg64_lsm(
    const float* __restrict__ Y, const int* __restrict__ rp,
    const int* __restrict__ col, const float* __restrict__ nd,
    const float* __restrict__ b3, float* __restrict__ out, int N) {
    int row = blockIdx.x * 4 + (threadIdx.x >> 6);
    if (row >= N) return;
    int lane = threadIdx.x & 63;
    int s = rp[row], e = rp[row + 1];
    float a0 = 0.f, a1 = 0.f, a2 = 0.f, a3 = 0.f;
    int i = s;
    for (; i + 3 < e; i += 4) {
        a0 += Y[(size_t)col[i]   * 64 + lane];
        a1 += Y[(size_t)col[i+1] * 64 + lane];
        a2 += Y[(size_t)col[i+2] * 64 + lane];
        a3 += Y[(size_t)col[i+3] * 64 + lane];
    }
    for (; i < e; ++i) a0 += Y[(size_t)col[i] * 64 + lane];
    float v = ((a0+a1)+(a2+a3)) * nd[row] + b3[lane];
    float m = v;
#pragma unroll
    for (int o = 32; o; o >>= 1) m = fmaxf(m, __shfl_xor(m, o));
    float ex = expf(v - m);
    float sum = ex;
#pragma unroll
    for (int o = 32; o; o >>= 1) sum += __shfl_xor(sum, o);
    out[(size_t)row * 64 + lane] = v - m - logf(sum);
}

// ======================= launch =======================
extern "C" void kernel_launch(void* const* d_in, const int* in_sizes, int n_in,
                              void* d_out, int out_size, void* d_ws, size_t ws_size,
                              hipStream_t stream) {
    const float* features = (const float*)d_in[0];
    const int*   src      = (const int*)d_in[1];
    const int*   dst      = (const int*)d_in[2];
    const float* W1       = (const float*)d_in[3];
    const float* b1       = (const float*)d_in[4];
    const float* W2       = (const float*)d_in[5];
    const float* b2       = (const float*)d_in[6];
    const float* W3       = (const float*)d_in[7];
    const float* b3       = (const float*)d_in[8];
    float* out = (float*)d_out;

    const int N = in_sizes[0] / D;   // 100000
    const int E = in_sizes[1];       // 1600000

    char* p = (char*)d_ws;
    float* A  = (float*)p; p += (size_t)N * D * sizeof(float);
    float* B  = (float*)p; p += (size_t)N * D * sizeof(float);
    int* col  = (int*)p;   p += (size_t)E * sizeof(int);
    int* rp   = (int*)p;   p += ((size_t)N + 4) * sizeof(int);
    int* fill = (int*)p;   p += (size_t)N * sizeof(int);
    int* dego = (int*)p;   p += (size_t)N * sizeof(int);   // memset region start
    int* degi = (int*)p;   p += (size_t)N * sizeof(int);
    float* ns = (float*)p; p += (size_t)N * sizeof(float);
    float* nd = (float*)p; p += (size_t)N * sizeof(float);
    int* bsum = (int*)p;   p += 4096 * sizeof(int);

    hipMemsetAsync(dego, 0, (size_t)2 * N * sizeof(int), stream);

    const int gN  = (N + 255) / 256;          // 391 (<512 for bsum scan)
    const int NBd = ((E >> 2) + 255) / 256;   // degree blocks (4 edges/thread)
    const int NBg = 2 * ((N + 63) / 64);      // T1 = F @ W1 blocks (J=128)
    const int S   = (NBd + NBg + NBd - 1) / NBd > 0 ? (NBd + NBg) / NBd : 1; // ~3
    const int Sx  = S < 1 ? 1 : S;

    // [degree histogram | T1 = F @ W1] fused: atomic-bound + VALU-bound overlap
    k_deg_gemm1<<<NBd + NBg, 256, 0, stream>>>(src, dst, E, NBd, Sx,
                                               dego, degi, features, W1, B, N);
    k_scan_block<<<gN, 256, 0, stream>>>(degi, rp, bsum, N);
    k_scan_bsum<<<1, 512, 0, stream>>>(bsum, gN);
    k_scan_add_norms<<<(N + 1 + 255) / 256, 256, 0, stream>>>(rp, bsum, fill,
                                                              dego, degi, ns, nd, N, E);
    k_csr_fill<<<NBd, 256, 0, stream>>>(src, dst, fill, col, E);

    // layer 1: h1s = relu(nd * sum_c ns[c]*T1[c] + b1) * ns    (T1 in B)
    k_spmm<true, true><<<(N + 7) / 8, 256, 0, stream>>>(B, rp, col, ns, nd, b1, A, N);
    // layer 2: T2 = h1s @ W2 ; h2s = relu(nd * sum T2[c] + b2) * ns
    dim3 g2((N + 63) / 64, 2);
    k_gemm<128><<<g2, 256, 0, stream>>>(A, W2, B, N);
    k_spmm<false, true><<<(N + 7) / 8, 256, 0, stream>>>(B, rp, col, ns, nd, b2, A, N);
    // layer 3: T3 = h2s @ W3 (64-dim) ; fused agg + b3 + log_softmax
    dim3 g3((N + 63) / 64, 1);
    k_gemm<64><<<g3, 256, 0, stream>>>(A, W3, B, N);
    k_agg64_lsm<<<(N + 3) / 4, 256, 0, stream>>>(B, rp, col, nd, b3, out, N);
}

// Round 3
// 685.914 us; speedup vs baseline: 1.2305x; 1.1618x over previous
//
#include <hip/hip_runtime.h>
#include <math.h>

#define D 128      // hidden / input dim
#define DO 64      // output dim

// ======================= GEMM from LDS tile =======================
// out[n0..n0+63, :JOUT] = Ms[64][128] @ W[128][JOUT]; j-loop internal so the
// tile (and its producer traffic) is read once. W is tiny (<=64KB) -> L2-hot.
template <int JOUT>
__device__ __forceinline__ void gemm_from_lds(
    float (*Ms)[132], const float* __restrict__ W,
    float* __restrict__ out, int N, int n0) {
    const int tid = threadIdx.x;
    const int tx = tid & 15;
    const int ty = tid >> 4;
    const float4* W4 = (const float4*)W;
#pragma unroll
    for (int jb = 0; jb < JOUT / 64; ++jb) {
        float acc[4][4] = {};
#pragma unroll 4
        for (int k = 0; k < 128; ++k) {
            float4 wv = W4[(size_t)k * (JOUT / 4) + jb * 16 + tx];
#pragma unroll
            for (int i = 0; i < 4; ++i) {
                float m = Ms[ty * 4 + i][k];
                acc[i][0] += m * wv.x; acc[i][1] += m * wv.y;
                acc[i][2] += m * wv.z; acc[i][3] += m * wv.w;
            }
        }
#pragma unroll
        for (int i = 0; i < 4; ++i) {
            int n = n0 + ty * 4 + i;
            if (n < N)
                ((float4*)out)[(size_t)n * (JOUT / 4) + jb * 16 + tx] =
                    make_float4(acc[i][0], acc[i][1], acc[i][2], acc[i][3]);
        }
    }
}

// ======================= fused: degree+rank atomics | T1 = F @ W1 =======================
// Degree blocks: atomic-bound (VALU ~0). The degi atomic's RETURN VALUE is the
// edge's rank within its dst row -> saved to rank[], making CSR fill atomic-free.
// GEMM blocks: VALU-bound. Interleaved so both pipes run on every CU.
__global__ __launch_bounds__(256) void k_deg_rank_gemm1(
    const int* __restrict__ src, const int* __restrict__ dst, int E,
    int NBd, int NBg,
    int* __restrict__ dego, int* __restrict__ degi, int* __restrict__ rank,
    const float* __restrict__ F, const float* __restrict__ W1,
    float* __restrict__ T1, int N) {
    __shared__ float Ms[64][132];
    const int bid = blockIdx.x;
    int did = -1, gid = -1;
    const int m2 = 2 * (NBd < NBg ? NBd : NBg);
    if (bid < m2) { if (bid & 1) gid = bid >> 1; else did = bid >> 1; }
    else { int r = bid - m2; if (NBd > NBg) did = (m2 >> 1) + r; else gid = (m2 >> 1) + r; }

    if (did >= 0) {
        const int nE4 = E >> 2;
        int idx = did * 256 + threadIdx.x;
        if (idx < nE4) {
            int4 s4 = ((const int4*)src)[idx];
            int4 d4 = ((const int4*)dst)[idx];
            int4 r4;
            r4.x = atomicAdd(&degi[d4.x], 1);
            r4.y = atomicAdd(&degi[d4.y], 1);
            r4.z = atomicAdd(&degi[d4.z], 1);
            r4.w = atomicAdd(&degi[d4.w], 1);
            atomicAdd(&dego[s4.x], 1); atomicAdd(&dego[s4.y], 1);
            atomicAdd(&dego[s4.z], 1); atomicAdd(&dego[s4.w], 1);
            ((int4*)rank)[idx] = r4;
        }
        if (idx == 0) {           // tail (E % 4)
            for (int i = nE4 * 4; i < E; ++i) {
                rank[i] = atomicAdd(&degi[dst[i]], 1);
                atomicAdd(&dego[src[i]], 1);
            }
        }
        return;
    }

    // GEMM block: stage F tile, multiply by W1 (both j-halves, F read once)
    const int n0 = gid * 64;
    const float4* M4 = (const float4*)F;
#pragma unroll
    for (int it = 0; it < 8; ++it) {
        int id = it * 256 + threadIdx.x;
        int nl = id >> 5, k4 = id & 31;
        float4 v = make_float4(0.f, 0.f, 0.f, 0.f);
        int n = n0 + nl;
        if (n < N) v = M4[(size_t)n * 32 + k4];
        *(float4*)&Ms[nl][k4 * 4] = v;
    }
    __syncthreads();
    gemm_from_lds<128>(Ms, W1, T1, N, n0);
}

// ======================= exclusive scan =======================
__global__ void k_scan_block(const int* __restrict__ cnt, int* __restrict__ rp,
                             int* __restrict__ bsum, int N) {
    __shared__ int sdat[256];
    int i = blockIdx.x * 256 + threadIdx.x;
    int v = (i < N) ? cnt[i] : 0;
    sdat[threadIdx.x] = v;
    __syncthreads();
    for (int off = 1; off < 256; off <<= 1) {
        int t = (threadIdx.x >= off) ? sdat[threadIdx.x - off] : 0;
        __syncthreads();
        sdat[threadIdx.x] += t;
        __syncthreads();
    }
    if (i < N) rp[i] = sdat[threadIdx.x] - v;   // exclusive
    if (threadIdx.x == 255) bsum[blockIdx.x] = sdat[255];
}

__global__ void k_scan_bsum(int* __restrict__ bsum, int NB) {
    __shared__ int sdat[512];
    int tid = threadIdx.x;
    int v = (tid < NB) ? bsum[tid] : 0;
    sdat[tid] = v;
    __syncthreads();
    for (int off = 1; off < 512; off <<= 1) {
        int t = (tid >= off) ? sdat[tid - off] : 0;
        __syncthreads();
        sdat[tid] += t;
        __syncthreads();
    }
    if (tid < NB) bsum[tid] = sdat[tid] - v;    // exclusive
}

__global__ void k_scan_add_norms(int* __restrict__ rp, const int* __restrict__ bsum,
                                 const int* __restrict__ dego, const int* __restrict__ degi,
                                 float* __restrict__ ns, float* __restrict__ nd,
                                 int N, int E) {
    int i = blockIdx.x * 256 + threadIdx.x;
    if (i < N) {
        rp[i] += bsum[i >> 8];
        int a = dego[i]; if (a < 1) a = 1;
        int b = degi[i]; if (b < 1) b = 1;
        ns[i] = rsqrtf((float)a);
        nd[i] = rsqrtf((float)b);
    }
    if (i == N) rp[N] = E;
}

// ======================= CSR scatter (atomic-free) =======================
__global__ void k_scatter(const int* __restrict__ src, const int* __restrict__ dst,
                          const int* __restrict__ rank, const int* __restrict__ rp,
                          int* __restrict__ col, int E) {
    const int nE4 = E >> 2;
    int idx = blockIdx.x * 256 + threadIdx.x;
    if (idx < nE4) {
        int4 s4 = ((const int4*)src)[idx];
        int4 d4 = ((const int4*)dst)[idx];
        int4 r4 = ((const int4*)rank)[idx];
        col[rp[d4.x] + r4.x] = s4.x;
        col[rp[d4.y] + r4.y] = s4.y;
        col[rp[d4.z] + r4.z] = s4.z;
        col[rp[d4.w] + r4.w] = s4.w;
    }
    if (idx == 0) {
        for (int i = nE4 * 4; i < E; ++i)
            col[rp[dst[i]] + rank[i]] = src[i];
    }
}

// ======================= fused: SpMM (gather-agg + epilogue) -> LDS -> GEMM =======================
// Phase A: tile row r: t = relu(nd[r]*sum_{c in N(r)} [ns[c]*]T[c] + bias)*ns[r] -> Ms
// Phase B: out = Ms @ W. Intermediate never touches global memory.
template <bool SCALE_SRC, int JOUT>
__global__ __launch_bounds__(256) void k_spmm_gemm(
    const float* __restrict__ T, const int* __restrict__ rp,
    const int* __restrict__ col, const float* __restrict__ ns,
    const float* __restrict__ nd, const float* __restrict__ bias,
    const float* __restrict__ W, float* __restrict__ out, int N) {
    __shared__ float Ms[64][132];
    const int n0 = blockIdx.x * 64;
    const int g = threadIdx.x >> 5;     // 8 groups of 32 lanes
    const int lane = threadIdx.x & 31;
    const float4* A4 = (const float4*)T;
    float4 bv = ((const float4*)bias)[lane];
#pragma unroll 1
    for (int rr = 0; rr < 8; ++rr) {
        int row = n0 + g * 8 + rr;
        if (row >= N) break;
        int s = rp[row], e = rp[row + 1];
        float4 a0 = make_float4(0.f,0.f,0.f,0.f), a1 = a0, a2 = a0, a3 = a0;
        int i = s;
        for (; i + 3 < e; i += 4) {
            int c0 = col[i], c1 = col[i+1], c2 = col[i+2], c3 = col[i+3];
            float4 v0 = A4[(size_t)c0 * 32 + lane];
            float4 v1 = A4[(size_t)c1 * 32 + lane];
            float4 v2 = A4[(size_t)c2 * 32 + lane];
            float4 v3 = A4[(size_t)c3 * 32 + lane];
            if (SCALE_SRC) {
                float s0 = ns[c0], s1 = ns[c1], s2 = ns[c2], s3 = ns[c3];
                a0.x = fmaf(v0.x,s0,a0.x); a0.y = fmaf(v0.y,s0,a0.y); a0.z = fmaf(v0.z,s0,a0.z); a0.w = fmaf(v0.w,s0,a0.w);
                a1.x = fmaf(v1.x,s1,a1.x); a1.y = fmaf(v1.y,s1,a1.y); a1.z = fmaf(v1.z,s1,a1.z); a1.w = fmaf(v1.w,s1,a1.w);
                a2.x = fmaf(v2.x,s2,a2.x); a2.y = fmaf(v2.y,s2,a2.y); a2.z = fmaf(v2.z,s2,a2.z); a2.w = fmaf(v2.w,s2,a2.w);
                a3.x = fmaf(v3.x,s3,a3.x); a3.y = fmaf(v3.y,s3,a3.y); a3.z = fmaf(v3.z,s3,a3.z); a3.w = fmaf(v3.w,s3,a3.w);
            } else {
                a0.x += v0.x; a0.y += v0.y; a0.z += v0.z; a0.w += v0.w;
                a1.x += v1.x; a1.y += v1.y; a1.z += v1.z; a1.w += v1.w;
                a2.x += v2.x; a2.y += v2.y; a2.z += v2.z; a2.w += v2.w;
                a3.x += v3.x; a3.y += v3.y; a3.z += v3.z; a3.w += v3.w;
            }
        }
        for (; i < e; ++i) {
            int c = col[i];
            float4 v = A4[(size_t)c * 32 + lane];
            float sc = SCALE_SRC ? ns[c] : 1.0f;
            a0.x = fmaf(v.x,sc,a0.x); a0.y = fmaf(v.y,sc,a0.y);
            a0.z = fmaf(v.z,sc,a0.z); a0.w = fmaf(v.w,sc,a0.w);
        }
        float4 t;
        t.x = (a0.x+a1.x) + (a2.x+a3.x);
        t.y = (a0.y+a1.y) + (a2.y+a3.y);
        t.z = (a0.z+a1.z) + (a2.z+a3.z);
        t.w = (a0.w+a1.w) + (a2.w+a3.w);
        float sd = nd[row], sr = ns[row];
        t.x = fmaxf(fmaf(t.x, sd, bv.x), 0.f) * sr;
        t.y = fmaxf(fmaf(t.y, sd, bv.y), 0.f) * sr;
        t.z = fmaxf(fmaf(t.z, sd, bv.z), 0.f) * sr;
        t.w = fmaxf(fmaf(t.w, sd, bv.w), 0.f) * sr;
        *(float4*)&Ms[row - n0][lane * 4] = t;
    }
    __syncthreads();
    gemm_from_lds<JOUT>(Ms, W, out, N, n0);
}

// ======================= layer-3 aggregate (64-dim) + bias + log_softmax =======================
__global__ __launch_bounds__(256) void k_agg64_lsm(
    const float* __restrict__ Y, const int* __restrict__ rp,
    const int* __restrict__ col, const float* __restrict__ nd,
    const float* __restrict__ b3, float* __restrict__ out, int N) {
    int row = blockIdx.x * 4 + (threadIdx.x >> 6);
    if (row >= N) return;
    int lane = threadIdx.x & 63;
    int s = rp[row], e = rp[row + 1];
    float a0 = 0.f, a1 = 0.f, a2 = 0.f, a3 = 0.f;
    int i = s;
    for (; i + 3 < e; i += 4) {
        a0 += Y[(size_t)col[i]   * 64 + lane];
        a1 += Y[(size_t)col[i+1] * 64 + lane];
        a2 += Y[(size_t)col[i+2] * 64 + lane];
        a3 += Y[(size_t)col[i+3] * 64 + lane];
    }
    for (; i < e; ++i) a0 += Y[(size_t)col[i] * 64 + lane];
    float v = ((a0+a1)+(a2+a3)) * nd[row] + b3[lane];
    float m = v;
#pragma unroll
    for (int o = 32; o; o >>= 1) m = fmaxf(m, __shfl_xor(m, o));
    float ex = expf(v - m);
    float sum = ex;
#pragma unroll
    for (int o = 32; o; o >>= 1) sum += __shfl_xor(sum, o);
    out[(size_t)row * 64 + lane] = v - m - logf(sum);
}

// ======================= launch =======================
extern "C" void kernel_launch(void* const* d_in, const int* in_sizes, int n_in,
                              void* d_out, int out_size, void* d_ws, size_t ws_size,
                              hipStream_t stream) {
    const float* features = (const float*)d_in[0];
    const int*   src      = (const int*)d_in[1];
    const int*   dst      = (const int*)d_in[2];
    const float* W1       = (const float*)d_in[3];
    const float* b1       = (const float*)d_in[4];
    const float* W2       = (const float*)d_in[5];
    const float* b2       = (const float*)d_in[6];
    const float* W3       = (const float*)d_in[7];
    const float* b3       = (const float*)d_in[8];
    float* out = (float*)d_out;

    const int N = in_sizes[0] / D;   // 100000
    const int E = in_sizes[1];       // 1600000

    char* p = (char*)d_ws;
    float* A    = (float*)p; p += (size_t)N * D * sizeof(float);
    float* B    = (float*)p; p += (size_t)N * D * sizeof(float);
    int* col    = (int*)p;   p += (size_t)E * sizeof(int);
    int* rank   = (int*)p;   p += (size_t)E * sizeof(int);
    int* rp     = (int*)p;   p += ((size_t)N + 4) * sizeof(int);
    int* dego   = (int*)p;   p += (size_t)N * sizeof(int);   // memset region start
    int* degi   = (int*)p;   p += (size_t)N * sizeof(int);
    float* ns   = (float*)p; p += (size_t)N * sizeof(float);
    float* nd   = (float*)p; p += (size_t)N * sizeof(float);
    int* bsum   = (int*)p;   p += 4096 * sizeof(int);

    hipMemsetAsync(dego, 0, (size_t)2 * N * sizeof(int), stream);

    const int gN  = (N + 255) / 256;          // 391 (<512 for bsum scan)
    const int NBd = ((E >> 2) + 255) / 256;   // degree blocks (4 edges/thread)
    const int NBn = (N + 63) / 64;            // node-tile blocks

    // K1: [degree+rank atomics | T1 = F @ W1] fused
    k_deg_rank_gemm1<<<NBd + NBn, 256, 0, stream>>>(src, dst, E, NBd, NBn,
                                                    dego, degi, rank,
                                                    features, W1, B, N);
    k_scan_block<<<gN, 256, 0, stream>>>(degi, rp, bsum, N);
    k_scan_bsum<<<1, 512, 0, stream>>>(bsum, gN);
    k_scan_add_norms<<<(N + 1 + 255) / 256, 256, 0, stream>>>(rp, bsum,
                                                              dego, degi, ns, nd, N, E);
    k_scatter<<<NBd, 256, 0, stream>>>(src, dst, rank, rp, col, E);

    // boundary 1->2: h1s = relu(nd*agg(ns*T1)+b1)*ns ; T2 = h1s @ W2   (B -> A)
    k_spmm_gemm<true, 128><<<NBn, 256, 0, stream>>>(B, rp, col, ns, nd, b1, W2, A, N);
    // boundary 2->3: h2s = relu(nd*agg(T2)+b2)*ns ; T3 = h2s @ W3      (A -> B)
    k_spmm_gemm<false, 64><<<NBn, 256, 0, stream>>>(A, rp, col, ns, nd, b2, W3, B, N);
    // final: out = log_softmax(nd*agg64(T3) + b3)
    k_agg64_lsm<<<(N + 3) / 4, 256, 0, stream>>>(B, rp, col, nd, b3, out, N);
}

// Round 4
// 570.038 us; speedup vs baseline: 1.4807x; 1.2033x over previous
//
#include <hip/hip_runtime.h>
#include <math.h>

#define D 128      // hidden / input dim
#define DO 64      // output dim

typedef unsigned int   uint32;
typedef unsigned short ushort16;

__device__ __forceinline__ unsigned short f2bf(float f) {
    uint32 u = __float_as_uint(f);
    u += 0x7FFFu + ((u >> 16) & 1u);        // round-to-nearest-even
    return (unsigned short)(u >> 16);
}
__device__ __forceinline__ float bf_lo(uint32 p) { return __uint_as_float(p << 16); }
__device__ __forceinline__ float bf_hi(uint32 p) { return __uint_as_float(p & 0xFFFF0000u); }

// ======================= GEMM from LDS tile -> bf16 out =======================
// out[n0..n0+63, :JOUT](bf16) = Ms[64][128](f32) @ W[128][JOUT](f32)
template <int JOUT>
__device__ __forceinline__ void gemm_from_lds(
    float (*Ms)[132], const float* __restrict__ W,
    unsigned short* __restrict__ out, int N, int n0) {
    const int tid = threadIdx.x;
    const int tx = tid & 15;
    const int ty = tid >> 4;
    const float4* W4 = (const float4*)W;
#pragma unroll
    for (int jb = 0; jb < JOUT / 64; ++jb) {
        float acc[4][4] = {};
#pragma unroll 4
        for (int k = 0; k < 128; ++k) {
            float4 wv = W4[(size_t)k * (JOUT / 4) + jb * 16 + tx];
#pragma unroll
            for (int i = 0; i < 4; ++i) {
                float m = Ms[ty * 4 + i][k];
                acc[i][0] += m * wv.x; acc[i][1] += m * wv.y;
                acc[i][2] += m * wv.z; acc[i][3] += m * wv.w;
            }
        }
#pragma unroll
        for (int i = 0; i < 4; ++i) {
            int n = n0 + ty * 4 + i;
            if (n < N) {
                ushort4 o;
                o.x = f2bf(acc[i][0]); o.y = f2bf(acc[i][1]);
                o.z = f2bf(acc[i][2]); o.w = f2bf(acc[i][3]);
                *(ushort4*)&out[(size_t)n * JOUT + jb * 64 + tx * 4] = o;
            }
        }
    }
}

// ======================= fused: degree+rank atomics | T1 = F @ W1 =======================
__global__ __launch_bounds__(256) void k_deg_rank_gemm1(
    const int* __restrict__ src, const int* __restrict__ dst, int E,
    int NBd, int NBg,
    int* __restrict__ dego, int* __restrict__ degi, int* __restrict__ rank,
    const float* __restrict__ F, const float* __restrict__ W1,
    unsigned short* __restrict__ T1, int N) {
    __shared__ float Ms[64][132];
    const int bid = blockIdx.x;
    int did = -1, gid = -1;
    const int m2 = 2 * (NBd < NBg ? NBd : NBg);
    if (bid < m2) { if (bid & 1) gid = bid >> 1; else did = bid >> 1; }
    else { int r = bid - m2; if (NBd > NBg) did = (m2 >> 1) + r; else gid = (m2 >> 1) + r; }

    if (did >= 0) {
        const int nE4 = E >> 2;
        int idx = did * 256 + threadIdx.x;
        if (idx < nE4) {
            int4 s4 = ((const int4*)src)[idx];
            int4 d4 = ((const int4*)dst)[idx];
            int4 r4;
            r4.x = atomicAdd(&degi[d4.x], 1);
            r4.y = atomicAdd(&degi[d4.y], 1);
            r4.z = atomicAdd(&degi[d4.z], 1);
            r4.w = atomicAdd(&degi[d4.w], 1);
            atomicAdd(&dego[s4.x], 1); atomicAdd(&dego[s4.y], 1);
            atomicAdd(&dego[s4.z], 1); atomicAdd(&dego[s4.w], 1);
            ((int4*)rank)[idx] = r4;
        }
        if (idx == 0) {           // tail (E % 4)
            for (int i = nE4 * 4; i < E; ++i) {
                rank[i] = atomicAdd(&degi[dst[i]], 1);
                atomicAdd(&dego[src[i]], 1);
            }
        }
        return;
    }

    const int n0 = gid * 64;
    const float4* M4 = (const float4*)F;
#pragma unroll
    for (int it = 0; it < 8; ++it) {
        int id = it * 256 + threadIdx.x;
        int nl = id >> 5, k4 = id & 31;
        float4 v = make_float4(0.f, 0.f, 0.f, 0.f);
        int n = n0 + nl;
        if (n < N) v = M4[(size_t)n * 32 + k4];
        *(float4*)&Ms[nl][k4 * 4] = v;
    }
    __syncthreads();
    gemm_from_lds<128>(Ms, W1, T1, N, n0);
}

// ======================= exclusive scan =======================
__global__ void k_scan_block(const int* __restrict__ cnt, int* __restrict__ rp,
                             int* __restrict__ bsum, int N) {
    __shared__ int sdat[256];
    int i = blockIdx.x * 256 + threadIdx.x;
    int v = (i < N) ? cnt[i] : 0;
    sdat[threadIdx.x] = v;
    __syncthreads();
    for (int off = 1; off < 256; off <<= 1) {
        int t = (threadIdx.x >= off) ? sdat[threadIdx.x - off] : 0;
        __syncthreads();
        sdat[threadIdx.x] += t;
        __syncthreads();
    }
    if (i < N) rp[i] = sdat[threadIdx.x] - v;
    if (threadIdx.x == 255) bsum[blockIdx.x] = sdat[255];
}

__global__ void k_scan_bsum(int* __restrict__ bsum, int NB) {
    __shared__ int sdat[512];
    int tid = threadIdx.x;
    int v = (tid < NB) ? bsum[tid] : 0;
    sdat[tid] = v;
    __syncthreads();
    for (int off = 1; off < 512; off <<= 1) {
        int t = (tid >= off) ? sdat[tid - off] : 0;
        __syncthreads();
        sdat[tid] += t;
        __syncthreads();
    }
    if (tid < NB) bsum[tid] = sdat[tid] - v;
}

__global__ void k_scan_add_norms(int* __restrict__ rp, const int* __restrict__ bsum,
                                 const int* __restrict__ dego, const int* __restrict__ degi,
                                 float* __restrict__ ns, float* __restrict__ nd,
                                 int N, int E) {
    int i = blockIdx.x * 256 + threadIdx.x;
    if (i < N) {
        rp[i] += bsum[i >> 8];
        int a = dego[i]; if (a < 1) a = 1;
        int b = degi[i]; if (b < 1) b = 1;
        ns[i] = rsqrtf((float)a);
        nd[i] = rsqrtf((float)b);
    }
    if (i == N) rp[N] = E;
}

// ======================= CSR scatter (atomic-free) =======================
__global__ void k_scatter(const int* __restrict__ src, const int* __restrict__ dst,
                          const int* __restrict__ rank, const int* __restrict__ rp,
                          int* __restrict__ col, int E) {
    const int nE4 = E >> 2;
    int idx = blockIdx.x * 256 + threadIdx.x;
    if (idx < nE4) {
        int4 s4 = ((const int4*)src)[idx];
        int4 d4 = ((const int4*)dst)[idx];
        int4 r4 = ((const int4*)rank)[idx];
        col[rp[d4.x] + r4.x] = s4.x;
        col[rp[d4.y] + r4.y] = s4.y;
        col[rp[d4.z] + r4.z] = s4.z;
        col[rp[d4.w] + r4.w] = s4.w;
    }
    if (idx == 0) {
        for (int i = nE4 * 4; i < E; ++i)
            col[rp[dst[i]] + rank[i]] = src[i];
    }
}

// ======================= fused: bf16-SpMM -> LDS(f32) -> GEMM -> bf16 =======================
// Phase A: row r: t = relu(nd[r]*sum_{c} [ns[c]*]T[c] + bias)*ns[r] -> Ms (f32)
// Phase B: out = Ms @ W (bf16 store). T rows are 128 bf16 (256 B); lane handles
// 4 dims via one 8B uint2 load per neighbor.
template <bool SCALE_SRC, int JOUT>
__global__ __launch_bounds__(256) void k_spmm_gemm(
    const unsigned short* __restrict__ T, const int* __restrict__ rp,
    const int* __restrict__ col, const float* __restrict__ ns,
    const float* __restrict__ nd, const float* __restrict__ bias,
    const float* __restrict__ W, unsigned short* __restrict__ out, int N) {
    __shared__ float Ms[64][132];
    const int n0 = blockIdx.x * 64;
    const int g = threadIdx.x >> 5;     // 8 groups of 32 lanes
    const int lane = threadIdx.x & 31;
    const uint2* T2 = (const uint2*)T;  // 32 x uint2 per row
    float4 bv = ((const float4*)bias)[lane];
#pragma unroll 1
    for (int rr = 0; rr < 8; ++rr) {
        int row = n0 + g * 8 + rr;
        if (row >= N) break;
        int s = rp[row], e = rp[row + 1];
        float4 a0 = make_float4(0.f,0.f,0.f,0.f), a1 = a0, a2 = a0, a3 = a0;
        int i = s;
        for (; i + 3 < e; i += 4) {
            int c0 = col[i], c1 = col[i+1], c2 = col[i+2], c3 = col[i+3];
            uint2 q0 = T2[(size_t)c0 * 32 + lane];
            uint2 q1 = T2[(size_t)c1 * 32 + lane];
            uint2 q2 = T2[(size_t)c2 * 32 + lane];
            uint2 q3 = T2[(size_t)c3 * 32 + lane];
            float s0 = SCALE_SRC ? ns[c0] : 1.0f;
            float s1 = SCALE_SRC ? ns[c1] : 1.0f;
            float s2 = SCALE_SRC ? ns[c2] : 1.0f;
            float s3 = SCALE_SRC ? ns[c3] : 1.0f;
            a0.x = fmaf(bf_lo(q0.x),s0,a0.x); a0.y = fmaf(bf_hi(q0.x),s0,a0.y);
            a0.z = fmaf(bf_lo(q0.y),s0,a0.z); a0.w = fmaf(bf_hi(q0.y),s0,a0.w);
            a1.x = fmaf(bf_lo(q1.x),s1,a1.x); a1.y = fmaf(bf_hi(q1.x),s1,a1.y);
            a1.z = fmaf(bf_lo(q1.y),s1,a1.z); a1.w = fmaf(bf_hi(q1.y),s1,a1.w);
            a2.x = fmaf(bf_lo(q2.x),s2,a2.x); a2.y = fmaf(bf_hi(q2.x),s2,a2.y);
            a2.z = fmaf(bf_lo(q2.y),s2,a2.z); a2.w = fmaf(bf_hi(q2.y),s2,a2.w);
            a3.x = fmaf(bf_lo(q3.x),s3,a3.x); a3.y = fmaf(bf_hi(q3.x),s3,a3.y);
            a3.z = fmaf(bf_lo(q3.y),s3,a3.z); a3.w = fmaf(bf_hi(q3.y),s3,a3.w);
        }
        for (; i < e; ++i) {
            int c = col[i];
            uint2 q = T2[(size_t)c * 32 + lane];
            float sc = SCALE_SRC ? ns[c] : 1.0f;
            a0.x = fmaf(bf_lo(q.x),sc,a0.x); a0.y = fmaf(bf_hi(q.x),sc,a0.y);
            a0.z = fmaf(bf_lo(q.y),sc,a0.z); a0.w = fmaf(bf_hi(q.y),sc,a0.w);
        }
        float4 t;
        t.x = (a0.x+a1.x) + (a2.x+a3.x);
        t.y = (a0.y+a1.y) + (a2.y+a3.y);
        t.z = (a0.z+a1.z) + (a2.z+a3.z);
        t.w = (a0.w+a1.w) + (a2.w+a3.w);
        float sd = nd[row], sr = ns[row];
        t.x = fmaxf(fmaf(t.x, sd, bv.x), 0.f) * sr;
        t.y = fmaxf(fmaf(t.y, sd, bv.y), 0.f) * sr;
        t.z = fmaxf(fmaf(t.z, sd, bv.z), 0.f) * sr;
        t.w = fmaxf(fmaf(t.w, sd, bv.w), 0.f) * sr;
        *(float4*)&Ms[row - n0][lane * 4] = t;
    }
    __syncthreads();
    gemm_from_lds<JOUT>(Ms, W, out, N, n0);
}

// ======================= layer-3: bf16 agg (64-dim) + bias + log_softmax =======================
// 32 lanes per row, 2 dims/lane (packed uint load per neighbor).
__global__ __launch_bounds__(256) void k_agg64_lsm(
    const unsigned short* __restrict__ Y, const int* __restrict__ rp,
    const int* __restrict__ col, const float* __restrict__ nd,
    const float* __restrict__ b3, float* __restrict__ out, int N) {
    int row = blockIdx.x * 8 + (threadIdx.x >> 5);
    if (row >= N) return;
    int lane = threadIdx.x & 31;
    const uint32* Y2 = (const uint32*)Y;    // 32 x uint per row
    int s = rp[row], e = rp[row + 1];
    float a0 = 0.f, a1 = 0.f, b0 = 0.f, b1 = 0.f,
          c0f = 0.f, c1f = 0.f, d0 = 0.f, d1 = 0.f;
    int i = s;
    for (; i + 3 < e; i += 4) {
        uint32 q0 = Y2[(size_t)col[i]   * 32 + lane];
        uint32 q1 = Y2[(size_t)col[i+1] * 32 + lane];
        uint32 q2 = Y2[(size_t)col[i+2] * 32 + lane];
        uint32 q3 = Y2[(size_t)col[i+3] * 32 + lane];
        a0 += bf_lo(q0); a1 += bf_hi(q0);
        b0 += bf_lo(q1); b1 += bf_hi(q1);
        c0f += bf_lo(q2); c1f += bf_hi(q2);
        d0 += bf_lo(q3); d1 += bf_hi(q3);
    }
    for (; i < e; ++i) {
        uint32 q = Y2[(size_t)col[i] * 32 + lane];
        a0 += bf_lo(q); a1 += bf_hi(q);
    }
    float sd = nd[row];
    float2 bb = ((const float2*)b3)[lane];
    float v0 = ((a0+b0)+(c0f+d0)) * sd + bb.x;
    float v1 = ((a1+b1)+(c1f+d1)) * sd + bb.y;
    float m = fmaxf(v0, v1);
#pragma unroll
    for (int o = 16; o; o >>= 1) m = fmaxf(m, __shfl_xor(m, o, 32));
    float ex = expf(v0 - m) + expf(v1 - m);
#pragma unroll
    for (int o = 16; o; o >>= 1) ex += __shfl_xor(ex, o, 32);
    float ls = m + logf(ex);
    ((float2*)out)[(size_t)row * 32 + lane] = make_float2(v0 - ls, v1 - ls);
}

// ======================= launch =======================
extern "C" void kernel_launch(void* const* d_in, const int* in_sizes, int n_in,
                              void* d_out, int out_size, void* d_ws, size_t ws_size,
                              hipStream_t stream) {
    const float* features = (const float*)d_in[0];
    const int*   src      = (const int*)d_in[1];
    const int*   dst      = (const int*)d_in[2];
    const float* W1       = (const float*)d_in[3];
    const float* b1       = (const float*)d_in[4];
    const float* W2       = (const float*)d_in[5];
    const float* b2       = (const float*)d_in[6];
    const float* W3       = (const float*)d_in[7];
    const float* b3       = (const float*)d_in[8];
    float* out = (float*)d_out;

    const int N = in_sizes[0] / D;   // 100000
    const int E = in_sizes[1];       // 1600000

    char* p = (char*)d_ws;
    unsigned short* A = (unsigned short*)p; p += (size_t)N * D * sizeof(unsigned short);
    unsigned short* B = (unsigned short*)p; p += (size_t)N * D * sizeof(unsigned short);
    int* col    = (int*)p;   p += (size_t)E * sizeof(int);
    int* rank   = (int*)p;   p += (size_t)E * sizeof(int);
    int* rp     = (int*)p;   p += ((size_t)N + 4) * sizeof(int);
    int* dego   = (int*)p;   p += (size_t)N * sizeof(int);   // memset region start
    int* degi   = (int*)p;   p += (size_t)N * sizeof(int);
    float* ns   = (float*)p; p += (size_t)N * sizeof(float);
    float* nd   = (float*)p; p += (size_t)N * sizeof(float);
    int* bsum   = (int*)p;   p += 4096 * sizeof(int);

    hipMemsetAsync(dego, 0, (size_t)2 * N * sizeof(int), stream);

    const int gN  = (N + 255) / 256;          // 391 (<512 for bsum scan)
    const int NBd = ((E >> 2) + 255) / 256;   // degree blocks (4 edges/thread)
    const int NBn = (N + 63) / 64;            // node-tile blocks

    // K1: [degree+rank atomics | T1 = F @ W1 (bf16 out)] fused
    k_deg_rank_gemm1<<<NBd + NBn, 256, 0, stream>>>(src, dst, E, NBd, NBn,
                                                    dego, degi, rank,
                                                    features, W1, B, N);
    k_scan_block<<<gN, 256, 0, stream>>>(degi, rp, bsum, N);
    k_scan_bsum<<<1, 512, 0, stream>>>(bsum, gN);
    k_scan_add_norms<<<(N + 1 + 255) / 256, 256, 0, stream>>>(rp, bsum,
                                                              dego, degi, ns, nd, N, E);
    k_scatter<<<NBd, 256, 0, stream>>>(src, dst, rank, rp, col, E);

    // boundary 1->2: h1s = relu(nd*agg(ns*T1)+b1)*ns ; T2 = h1s @ W2   (B -> A)
    k_spmm_gemm<true, 128><<<NBn, 256, 0, stream>>>(B, rp, col, ns, nd, b1, W2, A, N);
    // boundary 2->3: h2s = relu(nd*agg(T2)+b2)*ns ; T3 = h2s @ W3      (A -> B)
    k_spmm_gemm<false, 64><<<NBn, 256, 0, stream>>>(A, rp, col, ns, nd, b2, W3, B, N);
    // final: out = log_softmax(nd*agg64(T3) + b3)
    k_agg64_lsm<<<(N + 7) / 8, 256, 0, stream>>>(B, rp, col, nd, b3, out, N);
}

// Round 5
// 506.794 us; speedup vs baseline: 1.6654x; 1.1248x over previous
//
#include <hip/hip_runtime.h>
#include <math.h>

#define D 128      // hidden / input dim
#define DO 64      // output dim

#define CHUNK_BITS 14
#define CHUNK_SZ   16384     // nodes per histogram chunk (32KB LDS as 16-bit counters)
#define NSLICE     16        // edge slices (private copies) per chunk

typedef unsigned int uint32;

__device__ __forceinline__ unsigned short f2bf(float f) {
    uint32 u = __float_as_uint(f);
    u += 0x7FFFu + ((u >> 16) & 1u);        // round-to-nearest-even
    return (unsigned short)(u >> 16);
}
__device__ __forceinline__ float bf_lo(uint32 p) { return __uint_as_float(p << 16); }
__device__ __forceinline__ float bf_hi(uint32 p) { return __uint_as_float(p & 0xFFFF0000u); }

// ======================= 64-row GEMM from LDS tile -> bf16 (used by K1) =======================
__device__ __forceinline__ void gemm64_from_lds(
    float (*Ms)[132], const float* __restrict__ W,
    unsigned short* __restrict__ out, int N, int n0) {
    const int tid = threadIdx.x;
    const int tx = tid & 15;
    const int ty = tid >> 4;
    const float4* W4 = (const float4*)W;
#pragma unroll
    for (int jb = 0; jb < 2; ++jb) {
        float acc[4][4] = {};
#pragma unroll 4
        for (int k = 0; k < 128; ++k) {
            float4 wv = W4[(size_t)k * 32 + jb * 16 + tx];
#pragma unroll
            for (int i = 0; i < 4; ++i) {
                float m = Ms[ty * 4 + i][k];
                acc[i][0] += m * wv.x; acc[i][1] += m * wv.y;
                acc[i][2] += m * wv.z; acc[i][3] += m * wv.w;
            }
        }
#pragma unroll
        for (int i = 0; i < 4; ++i) {
            int n = n0 + ty * 4 + i;
            if (n < N) {
                ushort4 o;
                o.x = f2bf(acc[i][0]); o.y = f2bf(acc[i][1]);
                o.z = f2bf(acc[i][2]); o.w = f2bf(acc[i][3]);
                *(ushort4*)&out[(size_t)n * 128 + jb * 64 + tx * 4] = o;
            }
        }
    }
}

// ======================= K1: [degi atomics+rank | dego LDS-hist | T1 = F@W1] =======================
// Three block types interleaved with period P = degPer+gemmPer+1 so the
// fabric-atomic stream, LDS-histogram reads, and VALU GEMM overlap on every CU.
__global__ __launch_bounds__(256) void k_fused1(
    const int* __restrict__ src, const int* __restrict__ dst, int E,
    int NBd, int NBg, int NCHUNK, int degPer, int gemmPer,
    int* __restrict__ degi, int* __restrict__ rank, uint32* __restrict__ histbuf,
    const float* __restrict__ F, const float* __restrict__ W1,
    unsigned short* __restrict__ T1, int N) {
    __shared__ char smemraw[64 * 132 * 4];   // 33792 B, unioned across branches
    const int tid = threadIdx.x;
    const int P = degPer + gemmPer + 1;
    const int per = blockIdx.x / P;
    const int pos = blockIdx.x % P;

    if (pos < degPer) {
        // ---- degi atomic + rank (1 fabric atomic per edge; return = CSR rank) ----
        int did = per * degPer + pos;
        if (did >= NBd) return;
        const int nE4 = E >> 2;
        int idx = did * 256 + tid;
        if (idx < nE4) {
            int4 d4 = ((const int4*)dst)[idx];
            int4 r4;
            r4.x = atomicAdd(&degi[d4.x], 1);
            r4.y = atomicAdd(&degi[d4.y], 1);
            r4.z = atomicAdd(&degi[d4.z], 1);
            r4.w = atomicAdd(&degi[d4.w], 1);
            ((int4*)rank)[idx] = r4;
        }
        if (idx == 0) {
            for (int i = nE4 * 4; i < E; ++i)
                rank[i] = atomicAdd(&degi[dst[i]], 1);
        }
        return;
    }
    if (pos < degPer + gemmPer) {
        // ---- T1 = F @ W1 (bf16 out), 64-row tile ----
        int gid = per * gemmPer + (pos - degPer);
        if (gid >= NBg) return;
        float (*Ms)[132] = (float (*)[132])smemraw;
        const int n0 = gid * 64;
        const float4* M4 = (const float4*)F;
#pragma unroll
        for (int it = 0; it < 8; ++it) {
            int id = it * 256 + tid;
            int nl = id >> 5, k4 = id & 31;
            float4 v = make_float4(0.f, 0.f, 0.f, 0.f);
            int n = n0 + nl;
            if (n < N) v = M4[(size_t)n * 32 + k4];
            *(float4*)&Ms[nl][k4 * 4] = v;
        }
        __syncthreads();
        gemm64_from_lds(Ms, W1, T1, N, n0);
        return;
    }
    // ---- dego chunked LDS histogram (packed 16-bit counters) ----
    int hid = per;                       // [0, NCHUNK*NSLICE)
    if (hid >= NCHUNK * NSLICE) return;
    int chunk = hid / NSLICE;
    int slice = hid % NSLICE;
    int base = chunk << CHUNK_BITS;
    uint32* hist = (uint32*)smemraw;     // 8192 uints = 16384 x u16
    for (int w = tid; w < CHUNK_SZ / 2; w += 256) hist[w] = 0;
    __syncthreads();
    const int nE4 = E >> 2;
    int lo = (int)(((long long)slice * nE4) / NSLICE);
    int hi = (int)(((long long)(slice + 1) * nE4) / NSLICE);
    for (int idx = lo + tid; idx < hi; idx += 256) {
        int4 s4 = ((const int4*)src)[idx];
        unsigned o;
        o = (unsigned)(s4.x - base); if (o < CHUNK_SZ) atomicAdd(&hist[o >> 1], 1u << ((o & 1) * 16));
        o = (unsigned)(s4.y - base); if (o < CHUNK_SZ) atomicAdd(&hist[o >> 1], 1u << ((o & 1) * 16));
        o = (unsigned)(s4.z - base); if (o < CHUNK_SZ) atomicAdd(&hist[o >> 1], 1u << ((o & 1) * 16));
        o = (unsigned)(s4.w - base); if (o < CHUNK_SZ) atomicAdd(&hist[o >> 1], 1u << ((o & 1) * 16));
    }
    if (slice == NSLICE - 1 && tid == 0) {
        for (int i = nE4 * 4; i < E; ++i) {
            unsigned o = (unsigned)(src[i] - base);
            if (o < CHUNK_SZ) atomicAdd(&hist[o >> 1], 1u << ((o & 1) * 16));
        }
    }
    __syncthreads();
    uint32* outp = histbuf + (size_t)hid * (CHUNK_SZ / 2);
    for (int w = tid; w < CHUNK_SZ / 2; w += 256) outp[w] = hist[w];
}

// ======================= exclusive scan =======================
__global__ void k_scan_block(const int* __restrict__ cnt, int* __restrict__ rp,
                             int* __restrict__ bsum, int N) {
    __shared__ int sdat[256];
    int i = blockIdx.x * 256 + threadIdx.x;
    int v = (i < N) ? cnt[i] : 0;
    sdat[threadIdx.x] = v;
    __syncthreads();
    for (int off = 1; off < 256; off <<= 1) {
        int t = (threadIdx.x >= off) ? sdat[threadIdx.x - off] : 0;
        __syncthreads();
        sdat[threadIdx.x] += t;
        __syncthreads();
    }
    if (i < N) rp[i] = sdat[threadIdx.x] - v;
    if (threadIdx.x == 255) bsum[blockIdx.x] = sdat[255];
}

__global__ void k_scan_bsum(int* __restrict__ bsum, int NB) {
    __shared__ int sdat[512];
    int tid = threadIdx.x;
    int v = (tid < NB) ? bsum[tid] : 0;
    sdat[tid] = v;
    __syncthreads();
    for (int off = 1; off < 512; off <<= 1) {
        int t = (tid >= off) ? sdat[tid - off] : 0;
        __syncthreads();
        sdat[tid] += t;
        __syncthreads();
    }
    if (tid < NB) bsum[tid] = sdat[tid] - v;
}

// rp finalize + norms; out-degree merged from the NSLICE private hist copies.
__global__ void k_scan_add_norms(int* __restrict__ rp, const int* __restrict__ bsum,
                                 const int* __restrict__ degi,
                                 const uint32* __restrict__ histbuf,
                                 float* __restrict__ ns, float* __restrict__ nd,
                                 int N, int E) {
    int i = blockIdx.x * 256 + threadIdx.x;
    if (i < N) {
        rp[i] += bsum[i >> 8];
        int chunk = i >> CHUNK_BITS;
        int off = i & (CHUNK_SZ - 1);
        int w = off >> 1, h = (off & 1) * 16;
        int od = 0;
#pragma unroll
        for (int s = 0; s < NSLICE; ++s)
            od += (int)((histbuf[((size_t)(chunk * NSLICE + s)) * (CHUNK_SZ / 2) + w] >> h) & 0xFFFFu);
        int idg = degi[i];
        if (od < 1) od = 1;
        if (idg < 1) idg = 1;
        ns[i] = rsqrtf((float)od);
        nd[i] = rsqrtf((float)idg);
    }
    if (i == N) rp[N] = E;
}

// ======================= CSR scatter (atomic-free) =======================
__global__ void k_scatter(const int* __restrict__ src, const int* __restrict__ dst,
                          const int* __restrict__ rank, const int* __restrict__ rp,
                          int* __restrict__ col, int E) {
    const int nE4 = E >> 2;
    int idx = blockIdx.x * 256 + threadIdx.x;
    if (idx < nE4) {
        int4 s4 = ((const int4*)src)[idx];
        int4 d4 = ((const int4*)dst)[idx];
        int4 r4 = ((const int4*)rank)[idx];
        col[rp[d4.x] + r4.x] = s4.x;
        col[rp[d4.y] + r4.y] = s4.y;
        col[rp[d4.z] + r4.z] = s4.z;
        col[rp[d4.w] + r4.w] = s4.w;
    }
    if (idx == 0) {
        for (int i = nE4 * 4; i < E; ++i)
            col[rp[dst[i]] + rank[i]] = src[i];
    }
}

// ======================= fused bf16-SpMM -> LDS(f32) -> GEMM -> bf16, 32-row tile =======================
template <bool SCALE_SRC, int JOUT>
__global__ __launch_bounds__(256) void k_spmm_gemm(
    const unsigned short* __restrict__ T, const int* __restrict__ rp,
    const int* __restrict__ col, const float* __restrict__ ns,
    const float* __restrict__ nd, const float* __restrict__ bias,
    const float* __restrict__ W, unsigned short* __restrict__ out, int N) {
    __shared__ float Ms[32][132];
    const int n0 = blockIdx.x * 32;
    const int g = threadIdx.x >> 5;     // 8 groups of 32 lanes
    const int lane = threadIdx.x & 31;
    const uint2* T2 = (const uint2*)T;  // 32 x uint2 per row (128 bf16)
    float4 bv = ((const float4*)bias)[lane];
#pragma unroll 1
    for (int rr = 0; rr < 4; ++rr) {
        int row = n0 + g * 4 + rr;
        if (row < N) {
            int s = rp[row], e = rp[row + 1];
            float4 a0 = make_float4(0.f,0.f,0.f,0.f), a1 = a0, a2 = a0, a3 = a0;
            int i = s;
            for (; i + 7 < e; i += 8) {
                int c0 = col[i],   c1 = col[i+1], c2 = col[i+2], c3 = col[i+3];
                int c4 = col[i+4], c5 = col[i+5], c6 = col[i+6], c7 = col[i+7];
                uint2 q0 = T2[(size_t)c0 * 32 + lane];
                uint2 q1 = T2[(size_t)c1 * 32 + lane];
                uint2 q2 = T2[(size_t)c2 * 32 + lane];
                uint2 q3 = T2[(size_t)c3 * 32 + lane];
                uint2 q4 = T2[(size_t)c4 * 32 + lane];
                uint2 q5 = T2[(size_t)c5 * 32 + lane];
                uint2 q6 = T2[(size_t)c6 * 32 + lane];
                uint2 q7 = T2[(size_t)c7 * 32 + lane];
                float s0 = SCALE_SRC ? ns[c0] : 1.0f;
                float s1 = SCALE_SRC ? ns[c1] : 1.0f;
                float s2 = SCALE_SRC ? ns[c2] : 1.0f;
                float s3 = SCALE_SRC ? ns[c3] : 1.0f;
                float s4 = SCALE_SRC ? ns[c4] : 1.0f;
                float s5 = SCALE_SRC ? ns[c5] : 1.0f;
                float s6 = SCALE_SRC ? ns[c6] : 1.0f;
                float s7 = SCALE_SRC ? ns[c7] : 1.0f;
                a0.x = fmaf(bf_lo(q0.x),s0,a0.x); a0.y = fmaf(bf_hi(q0.x),s0,a0.y);
                a0.z = fmaf(bf_lo(q0.y),s0,a0.z); a0.w = fmaf(bf_hi(q0.y),s0,a0.w);
                a1.x = fmaf(bf_lo(q1.x),s1,a1.x); a1.y = fmaf(bf_hi(q1.x),s1,a1.y);
                a1.z = fmaf(bf_lo(q1.y),s1,a1.z); a1.w = fmaf(bf_hi(q1.y),s1,a1.w);
                a2.x = fmaf(bf_lo(q2.x),s2,a2.x); a2.y = fmaf(bf_hi(q2.x),s2,a2.y);
                a2.z = fmaf(bf_lo(q2.y),s2,a2.z); a2.w = fmaf(bf_hi(q2.y),s2,a2.w);
                a3.x = fmaf(bf_lo(q3.x),s3,a3.x); a3.y = fmaf(bf_hi(q3.x),s3,a3.y);
                a3.z = fmaf(bf_lo(q3.y),s3,a3.z); a3.w = fmaf(bf_hi(q3.y),s3,a3.w);
                a0.x = fmaf(bf_lo(q4.x),s4,a0.x); a0.y = fmaf(bf_hi(q4.x),s4,a0.y);
                a0.z = fmaf(bf_lo(q4.y),s4,a0.z); a0.w = fmaf(bf_hi(q4.y),s4,a0.w);
                a1.x = fmaf(bf_lo(q5.x),s5,a1.x); a1.y = fmaf(bf_hi(q5.x),s5,a1.y);
                a1.z = fmaf(bf_lo(q5.y),s5,a1.z); a1.w = fmaf(bf_hi(q5.y),s5,a1.w);
                a2.x = fmaf(bf_lo(q6.x),s6,a2.x); a2.y = fmaf(bf_hi(q6.x),s6,a2.y);
                a2.z = fmaf(bf_lo(q6.y),s6,a2.z); a2.w = fmaf(bf_hi(q6.y),s6,a2.w);
                a3.x = fmaf(bf_lo(q7.x),s7,a3.x); a3.y = fmaf(bf_hi(q7.x),s7,a3.y);
                a3.z = fmaf(bf_lo(q7.y),s7,a3.z); a3.w = fmaf(bf_hi(q7.y),s7,a3.w);
            }
            for (; i + 3 < e; i += 4) {
                int c0 = col[i], c1 = col[i+1], c2 = col[i+2], c3 = col[i+3];
                uint2 q0 = T2[(size_t)c0 * 32 + lane];
                uint2 q1 = T2[(size_t)c1 * 32 + lane];
                uint2 q2 = T2[(size_t)c2 * 32 + lane];
                uint2 q3 = T2[(size_t)c3 * 32 + lane];
                float s0 = SCALE_SRC ? ns[c0] : 1.0f;
                float s1 = SCALE_SRC ? ns[c1] : 1.0f;
                float s2 = SCALE_SRC ? ns[c2] : 1.0f;
                float s3 = SCALE_SRC ? ns[c3] : 1.0f;
                a0.x = fmaf(bf_lo(q0.x),s0,a0.x); a0.y = fmaf(bf_hi(q0.x),s0,a0.y);
                a0.z = fmaf(bf_lo(q0.y),s0,a0.z); a0.w = fmaf(bf_hi(q0.y),s0,a0.w);
                a1.x = fmaf(bf_lo(q1.x),s1,a1.x); a1.y = fmaf(bf_hi(q1.x),s1,a1.y);
                a1.z = fmaf(bf_lo(q1.y),s1,a1.z); a1.w = fmaf(bf_hi(q1.y),s1,a1.w);
                a2.x = fmaf(bf_lo(q2.x),s2,a2.x); a2.y = fmaf(bf_hi(q2.x),s2,a2.y);
                a2.z = fmaf(bf_lo(q2.y),s2,a2.z); a2.w = fmaf(bf_hi(q2.y),s2,a2.w);
                a3.x = fmaf(bf_lo(q3.x),s3,a3.x); a3.y = fmaf(bf_hi(q3.x),s3,a3.y);
                a3.z = fmaf(bf_lo(q3.y),s3,a3.z); a3.w = fmaf(bf_hi(q3.y),s3,a3.w);
            }
            for (; i < e; ++i) {
                int c = col[i];
                uint2 q = T2[(size_t)c * 32 + lane];
                float sc = SCALE_SRC ? ns[c] : 1.0f;
                a0.x = fmaf(bf_lo(q.x),sc,a0.x); a0.y = fmaf(bf_hi(q.x),sc,a0.y);
                a0.z = fmaf(bf_lo(q.y),sc,a0.z); a0.w = fmaf(bf_hi(q.y),sc,a0.w);
            }
            float4 t;
            t.x = (a0.x+a1.x) + (a2.x+a3.x);
            t.y = (a0.y+a1.y) + (a2.y+a3.y);
            t.z = (a0.z+a1.z) + (a2.z+a3.z);
            t.w = (a0.w+a1.w) + (a2.w+a3.w);
            float sd = nd[row], sr = ns[row];
            t.x = fmaxf(fmaf(t.x, sd, bv.x), 0.f) * sr;
            t.y = fmaxf(fmaf(t.y, sd, bv.y), 0.f) * sr;
            t.z = fmaxf(fmaf(t.z, sd, bv.z), 0.f) * sr;
            t.w = fmaxf(fmaf(t.w, sd, bv.w), 0.f) * sr;
            *(float4*)&Ms[row - n0][lane * 4] = t;
        }
    }
    __syncthreads();
    const float4* W4 = (const float4*)W;
    if (JOUT == 128) {
        const int tx = threadIdx.x & 31;
        const int ty = threadIdx.x >> 5;
        float acc[4][4] = {};
#pragma unroll 4
        for (int k = 0; k < 128; ++k) {
            float4 wv = W4[(size_t)k * 32 + tx];
#pragma unroll
            for (int i = 0; i < 4; ++i) {
                float m = Ms[ty * 4 + i][k];
                acc[i][0] += m * wv.x; acc[i][1] += m * wv.y;
                acc[i][2] += m * wv.z; acc[i][3] += m * wv.w;
            }
        }
#pragma unroll
        for (int i = 0; i < 4; ++i) {
            int n = n0 + ty * 4 + i;
            if (n < N) {
                ushort4 o;
                o.x = f2bf(acc[i][0]); o.y = f2bf(acc[i][1]);
                o.z = f2bf(acc[i][2]); o.w = f2bf(acc[i][3]);
                *(ushort4*)&out[(size_t)n * 128 + tx * 4] = o;
            }
        }
    } else {                            // JOUT == 64
        const int tx = threadIdx.x & 15;
        const int ty = threadIdx.x >> 4;
        float acc[2][4] = {};
#pragma unroll 4
        for (int k = 0; k < 128; ++k) {
            float4 wv = W4[(size_t)k * 16 + tx];
#pragma unroll
            for (int i = 0; i < 2; ++i) {
                float m = Ms[ty * 2 + i][k];
                acc[i][0] += m * wv.x; acc[i][1] += m * wv.y;
                acc[i][2] += m * wv.z; acc[i][3] += m * wv.w;
            }
        }
#pragma unroll
        for (int i = 0; i < 2; ++i) {
            int n = n0 + ty * 2 + i;
            if (n < N) {
                ushort4 o;
                o.x = f2bf(acc[i][0]); o.y = f2bf(acc[i][1]);
                o.z = f2bf(acc[i][2]); o.w = f2bf(acc[i][3]);
                *(ushort4*)&out[(size_t)n * 64 + tx * 4] = o;
            }
        }
    }
}

// ======================= layer-3: bf16 agg (64-dim) + bias + log_softmax =======================
__global__ __launch_bounds__(256) void k_agg64_lsm(
    const unsigned short* __restrict__ Y, const int* __restrict__ rp,
    const int* __restrict__ col, const float* __restrict__ nd,
    const float* __restrict__ b3, float* __restrict__ out, int N) {
    int row = blockIdx.x * 8 + (threadIdx.x >> 5);
    if (row >= N) return;
    int lane = threadIdx.x & 31;
    const uint32* Y2 = (const uint32*)Y;    // 32 x uint per row
    int s = rp[row], e = rp[row + 1];
    float lo0=0.f,lo1=0.f,lo2=0.f,lo3=0.f, hi0=0.f,hi1=0.f,hi2=0.f,hi3=0.f;
    int i = s;
    for (; i + 7 < e; i += 8) {
        uint32 q0 = Y2[(size_t)col[i]   * 32 + lane];
        uint32 q1 = Y2[(size_t)col[i+1] * 32 + lane];
        uint32 q2 = Y2[(size_t)col[i+2] * 32 + lane];
        uint32 q3 = Y2[(size_t)col[i+3] * 32 + lane];
        uint32 q4 = Y2[(size_t)col[i+4] * 32 + lane];
        uint32 q5 = Y2[(size_t)col[i+5] * 32 + lane];
        uint32 q6 = Y2[(size_t)col[i+6] * 32 + lane];
        uint32 q7 = Y2[(size_t)col[i+7] * 32 + lane];
        lo0 += bf_lo(q0); hi0 += bf_hi(q0);
        lo1 += bf_lo(q1); hi1 += bf_hi(q1);
        lo2 += bf_lo(q2); hi2 += bf_hi(q2);
        lo3 += bf_lo(q3); hi3 += bf_hi(q3);
        lo0 += bf_lo(q4); hi0 += bf_hi(q4);
        lo1 += bf_lo(q5); hi1 += bf_hi(q5);
        lo2 += bf_lo(q6); hi2 += bf_hi(q6);
        lo3 += bf_lo(q7); hi3 += bf_hi(q7);
    }
    for (; i < e; ++i) {
        uint32 q = Y2[(size_t)col[i] * 32 + lane];
        lo0 += bf_lo(q); hi0 += bf_hi(q);
    }
    float sd = nd[row];
    float2 bb = ((const float2*)b3)[lane];
    float v0 = ((lo0+lo1)+(lo2+lo3)) * sd + bb.x;
    float v1 = ((hi0+hi1)+(hi2+hi3)) * sd + bb.y;
    float m = fmaxf(v0, v1);
#pragma unroll
    for (int o = 16; o; o >>= 1) m = fmaxf(m, __shfl_xor(m, o, 32));
    float ex = expf(v0 - m) + expf(v1 - m);
#pragma unroll
    for (int o = 16; o; o >>= 1) ex += __shfl_xor(ex, o, 32);
    float ls = m + logf(ex);
    ((float2*)out)[(size_t)row * 32 + lane] = make_float2(v0 - ls, v1 - ls);
}

// ======================= launch =======================
extern "C" void kernel_launch(void* const* d_in, const int* in_sizes, int n_in,
                              void* d_out, int out_size, void* d_ws, size_t ws_size,
                              hipStream_t stream) {
    const float* features = (const float*)d_in[0];
    const int*   src      = (const int*)d_in[1];
    const int*   dst      = (const int*)d_in[2];
    const float* W1       = (const float*)d_in[3];
    const float* b1       = (const float*)d_in[4];
    const float* W2       = (const float*)d_in[5];
    const float* b2       = (const float*)d_in[6];
    const float* W3       = (const float*)d_in[7];
    const float* b3       = (const float*)d_in[8];
    float* out = (float*)d_out;

    const int N = in_sizes[0] / D;   // 100000
    const int E = in_sizes[1];       // 1600000

    const int NCHUNK = (N + CHUNK_SZ - 1) >> CHUNK_BITS;       // 7
    const int NBh = NCHUNK * NSLICE;                           // 112

    char* p = (char*)d_ws;
    unsigned short* A = (unsigned short*)p; p += (size_t)N * D * sizeof(unsigned short);
    unsigned short* B = (unsigned short*)p; p += (size_t)N * D * sizeof(unsigned short);
    int* col    = (int*)p;   p += (size_t)E * sizeof(int);
    int* rank   = (int*)p;   p += (size_t)E * sizeof(int);
    int* rp     = (int*)p;   p += ((size_t)N + 4) * sizeof(int);
    int* degi   = (int*)p;   p += (size_t)N * sizeof(int);     // memset region
    float* ns   = (float*)p; p += (size_t)N * sizeof(float);
    float* nd   = (float*)p; p += (size_t)N * sizeof(float);
    int* bsum   = (int*)p;   p += 4096 * sizeof(int);
    uint32* histbuf = (uint32*)p; p += (size_t)NBh * (CHUNK_SZ / 2) * sizeof(uint32);

    hipMemsetAsync(degi, 0, (size_t)N * sizeof(int), stream);

    const int gN  = (N + 255) / 256;          // 391 (<512 for bsum scan)
    const int NBd = ((E >> 2) + 255) / 256;   // 1563 atomic blocks (4 edges/thread)
    const int NBg = (N + 63) / 64;            // 1563 T1-GEMM blocks (64-row tiles)
    const int periods = NBh;
    const int degPer  = (NBd + periods - 1) / periods;         // 14
    const int gemmPer = (NBg + periods - 1) / periods;         // 14
    const int P = degPer + gemmPer + 1;                        // 29
    const int G1 = P * periods;                                // 3248

    // K1: degi atomics+rank | dego LDS-hist | T1 = F @ W1 (bf16)
    k_fused1<<<G1, 256, 0, stream>>>(src, dst, E, NBd, NBg, NCHUNK, degPer, gemmPer,
                                     degi, rank, histbuf, features, W1, B, N);
    k_scan_block<<<gN, 256, 0, stream>>>(degi, rp, bsum, N);
    k_scan_bsum<<<1, 512, 0, stream>>>(bsum, gN);
    k_scan_add_norms<<<(N + 1 + 255) / 256, 256, 0, stream>>>(rp, bsum, degi, histbuf,
                                                              ns, nd, N, E);
    k_scatter<<<NBd, 256, 0, stream>>>(src, dst, rank, rp, col, E);

    const int NBn32 = (N + 31) / 32;          // 3125 (32-row tiles)
    // boundary 1->2: h1s = relu(nd*agg(ns*T1)+b1)*ns ; T2 = h1s @ W2   (B -> A)
    k_spmm_gemm<true, 128><<<NBn32, 256, 0, stream>>>(B, rp, col, ns, nd, b1, W2, A, N);
    // boundary 2->3: h2s = relu(nd*agg(T2)+b2)*ns ; T3 = h2s @ W3      (A -> B)
    k_spmm_gemm<false, 64><<<NBn32, 256, 0, stream>>>(A, rp, col, ns, nd, b2, W3, B, N);
    // final: out = log_softmax(nd*agg64(T3) + b3)
    k_agg64_lsm<<<(N + 7) / 8, 256, 0, stream>>>(B, rp, col, nd, b3, out, N);
}

// Round 6
// 476.151 us; speedup vs baseline: 1.7726x; 1.0644x over previous
//
#include <hip/hip_runtime.h>
#include <math.h>

#define D 128
#define DO 64

#define CHUNK_BITS 14
#define CHUNK_SZ   16384          // nodes per chunk (32KB LDS as u16 counters)
#define HWORDS     (CHUNK_SZ/2)   // 8192 u32 words
#define NSLICE     64             // edge slices per chunk

typedef unsigned int uint32;

__device__ __forceinline__ unsigned short f2bf(float f) {
    uint32 u = __float_as_uint(f);
    u += 0x7FFFu + ((u >> 16) & 1u);
    return (unsigned short)(u >> 16);
}
__device__ __forceinline__ float bf_lo(uint32 p) { return __uint_as_float(p << 16); }
__device__ __forceinline__ float bf_hi(uint32 p) { return __uint_as_float(p & 0xFFFF0000u); }
__device__ __forceinline__ void acc2(float4& a, uint2 q) {
    a.x += bf_lo(q.x); a.y += bf_hi(q.x);
    a.z += bf_lo(q.y); a.w += bf_hi(q.y);
}

// ======================= 64-row GEMM from LDS tile -> bf16 (K1) =======================
__device__ __forceinline__ void gemm64_from_lds(
    float (*Ms)[132], const float* __restrict__ W,
    unsigned short* __restrict__ out, int N, int n0) {
    const int tx = threadIdx.x & 15;
    const int ty = threadIdx.x >> 4;
    const float4* W4 = (const float4*)W;
#pragma unroll
    for (int jb = 0; jb < 2; ++jb) {
        float acc[4][4] = {};
#pragma unroll 4
        for (int k = 0; k < 128; ++k) {
            float4 wv = W4[(size_t)k * 32 + jb * 16 + tx];
#pragma unroll
            for (int i = 0; i < 4; ++i) {
                float m = Ms[ty * 4 + i][k];
                acc[i][0] += m * wv.x; acc[i][1] += m * wv.y;
                acc[i][2] += m * wv.z; acc[i][3] += m * wv.w;
            }
        }
#pragma unroll
        for (int i = 0; i < 4; ++i) {
            int n = n0 + ty * 4 + i;
            if (n < N) {
                ushort4 o;
                o.x = f2bf(acc[i][0]); o.y = f2bf(acc[i][1]);
                o.z = f2bf(acc[i][2]); o.w = f2bf(acc[i][3]);
                *(ushort4*)&out[(size_t)n * 128 + jb * 64 + tx * 4] = o;
            }
        }
    }
}

// ======================= K1: [src-hist | dst-hist | T1 = F@W1] — NO fabric atomics =======================
__global__ __launch_bounds__(256) void k_hist_gemm1(
    const int* __restrict__ src, const int* __restrict__ dst, int E,
    int NH, int NBg, int gemmPer,
    uint32* __restrict__ histS, uint32* __restrict__ histD,
    const float* __restrict__ F, const float* __restrict__ W1,
    unsigned short* __restrict__ T1, int N) {
    __shared__ char smemraw[64 * 132 * 4];
    const int tid = threadIdx.x;
    const int P = 1 + gemmPer;
    const int per = blockIdx.x / P;
    const int pos = blockIdx.x % P;

    if (pos == 0) {
        // histogram block: per in [0, 2*NH); first half = dst, second = src
        if (per >= 2 * NH) return;
        bool isS = per >= NH;
        int h = isS ? per - NH : per;
        int chunk = h / NSLICE, slice = h % NSLICE;
        const int* key = isS ? src : dst;
        uint32* hist = (uint32*)smemraw;
        for (int w = tid; w < HWORDS; w += 256) hist[w] = 0;
        __syncthreads();
        int base = chunk << CHUNK_BITS;
        const int nE4 = E >> 2;
        int lo = (int)(((long long)slice * nE4) / NSLICE);
        int hi = (int)(((long long)(slice + 1) * nE4) / NSLICE);
        for (int idx = lo + tid; idx < hi; idx += 256) {
            int4 k4 = ((const int4*)key)[idx];
            unsigned o;
            o = (unsigned)(k4.x - base); if (o < CHUNK_SZ) atomicAdd(&hist[o >> 1], 1u << ((o & 1) * 16));
            o = (unsigned)(k4.y - base); if (o < CHUNK_SZ) atomicAdd(&hist[o >> 1], 1u << ((o & 1) * 16));
            o = (unsigned)(k4.z - base); if (o < CHUNK_SZ) atomicAdd(&hist[o >> 1], 1u << ((o & 1) * 16));
            o = (unsigned)(k4.w - base); if (o < CHUNK_SZ) atomicAdd(&hist[o >> 1], 1u << ((o & 1) * 16));
        }
        if (slice == NSLICE - 1 && tid == 0) {
            for (int i = nE4 * 4; i < E; ++i) {
                unsigned o = (unsigned)(key[i] - base);
                if (o < CHUNK_SZ) atomicAdd(&hist[o >> 1], 1u << ((o & 1) * 16));
            }
        }
        __syncthreads();
        uint32* outp = (isS ? histS : histD) + (size_t)h * HWORDS;
        for (int w = tid; w < HWORDS; w += 256) outp[w] = hist[w];
        return;
    }
    // GEMM block: T1 = F @ W1 (bf16)
    int gid = per * gemmPer + (pos - 1);
    if (gid >= NBg) return;
    float (*Ms)[132] = (float (*)[132])smemraw;
    const int n0 = gid * 64;
    const float4* M4 = (const float4*)F;
#pragma unroll
    for (int it = 0; it < 8; ++it) {
        int id = it * 256 + tid;
        int nl = id >> 5, k4 = id & 31;
        float4 v = make_float4(0.f, 0.f, 0.f, 0.f);
        int n = n0 + nl;
        if (n < N) v = M4[(size_t)n * 32 + k4];
        *(float4*)&Ms[nl][k4 * 4] = v;
    }
    __syncthreads();
    gemm64_from_lds(Ms, W1, T1, N, n0);
}

// ======================= merge hists -> degrees/norms; histD -> per-slice prefix (in place) =======================
// One thread per u32 word = 2 adjacent nodes (avoids RMW races on shared words).
__global__ void k_merge_norms(uint32* __restrict__ histS, uint32* __restrict__ histD,
                              int* __restrict__ degi, float* __restrict__ ns,
                              float* __restrict__ nd, int N, int NCHUNK) {
    int w = blockIdx.x * 256 + threadIdx.x;
    if (w >= NCHUNK * HWORDS) return;
    int chunk = w / HWORDS, ww = w % HWORDS;
    int n0 = (chunk << CHUNK_BITS) + ww * 2;
    if (n0 >= N) return;
    size_t basehist = ((size_t)chunk * NSLICE) * HWORDS + ww;
    uint32 runD = 0, runS = 0;
#pragma unroll 4
    for (int s = 0; s < NSLICE; ++s) {
        size_t idx = basehist + (size_t)s * HWORDS;
        uint32 c = histD[idx];
        histD[idx] = runD;          // exclusive per-slice prefix (packed u16 halves)
        runD += c;                  // no cross-half carry: counts << 65536
        runS += histS[idx];
    }
    int d0 = runD & 0xFFFF, d1 = runD >> 16;
    int o0 = runS & 0xFFFF, o1 = runS >> 16;
    degi[n0] = d0;
    ns[n0] = rsqrtf((float)(o0 < 1 ? 1 : o0));
    nd[n0] = rsqrtf((float)(d0 < 1 ? 1 : d0));
    if (n0 + 1 < N) {
        degi[n0 + 1] = d1;
        ns[n0 + 1] = rsqrtf((float)(o1 < 1 ? 1 : o1));
        nd[n0 + 1] = rsqrtf((float)(d1 < 1 ? 1 : d1));
    }
}

// ======================= exclusive scan =======================
__global__ void k_scan_block(const int* __restrict__ cnt, int* __restrict__ rp,
                             int* __restrict__ bsum, int N) {
    __shared__ int sdat[256];
    int i = blockIdx.x * 256 + threadIdx.x;
    int v = (i < N) ? cnt[i] : 0;
    sdat[threadIdx.x] = v;
    __syncthreads();
    for (int off = 1; off < 256; off <<= 1) {
        int t = (threadIdx.x >= off) ? sdat[threadIdx.x - off] : 0;
        __syncthreads();
        sdat[threadIdx.x] += t;
        __syncthreads();
    }
    if (i < N) rp[i] = sdat[threadIdx.x] - v;
    if (threadIdx.x == 255) bsum[blockIdx.x] = sdat[255];
}

__global__ void k_scan_bsum(int* __restrict__ bsum, int NB) {
    __shared__ int sdat[512];
    int tid = threadIdx.x;
    int v = (tid < NB) ? bsum[tid] : 0;
    sdat[tid] = v;
    __syncthreads();
    for (int off = 1; off < 512; off <<= 1) {
        int t = (tid >= off) ? sdat[tid - off] : 0;
        __syncthreads();
        sdat[tid] += t;
        __syncthreads();
    }
    if (tid < NB) bsum[tid] = sdat[tid] - v;
}

__global__ void k_scan_add(int* __restrict__ rp, const int* __restrict__ bsum,
                           int N, int E) {
    int i = blockIdx.x * 256 + threadIdx.x;
    if (i < N) rp[i] += bsum[i >> 8];
    if (i == N) rp[N] = E;
}

// ======================= T1 *= ns (fold src-norm once; spmm layers become pure adds) =======================
__global__ void k_rescale(unsigned short* __restrict__ T1, const float* __restrict__ ns, int N) {
    int i = blockIdx.x * 256 + threadIdx.x;    // over N*32 uint2
    if (i < N * 32) {
        float s = ns[i >> 5];
        uint2 q = ((uint2*)T1)[i];
        ushort4 o;
        o.x = f2bf(bf_lo(q.x) * s); o.y = f2bf(bf_hi(q.x) * s);
        o.z = f2bf(bf_lo(q.y) * s); o.w = f2bf(bf_hi(q.y) * s);
        ((uint2*)T1)[i] = *(uint2*)&o;
    }
}

// ======================= rank + CSR scatter — LDS atomics only =======================
// LDS counters seeded with the per-slice prefix P[s][d]; the packed LDS atomicAdd
// return IS (prefix + local rank). pos = rp[d] + extract16(old).
__global__ __launch_bounds__(256) void k_rank_scatter(
    const int* __restrict__ src, const int* __restrict__ dst, int E,
    const uint32* __restrict__ histD, const int* __restrict__ rp,
    int* __restrict__ col) {
    __shared__ uint32 cnt[HWORDS];          // 32 KB
    const int tid = threadIdx.x;
    int chunk = blockIdx.x / NSLICE, slice = blockIdx.x % NSLICE;
    const uint32* Pslice = histD + ((size_t)(chunk * NSLICE + slice)) * HWORDS;
    for (int w = tid; w < HWORDS; w += 256) cnt[w] = Pslice[w];
    __syncthreads();
    int base = chunk << CHUNK_BITS;
    const int nE4 = E >> 2;
    int lo = (int)(((long long)slice * nE4) / NSLICE);
    int hi = (int)(((long long)(slice + 1) * nE4) / NSLICE);
    for (int idx = lo + tid; idx < hi; idx += 256) {
        int4 s4 = ((const int4*)src)[idx];
        int4 d4 = ((const int4*)dst)[idx];
        unsigned o;
        o = (unsigned)(d4.x - base);
        if (o < CHUNK_SZ) {
            uint32 old = atomicAdd(&cnt[o >> 1], 1u << ((o & 1) * 16));
            col[rp[d4.x] + ((old >> ((o & 1) * 16)) & 0xFFFF)] = s4.x;
        }
        o = (unsigned)(d4.y - base);
        if (o < CHUNK_SZ) {
            uint32 old = atomicAdd(&cnt[o >> 1], 1u << ((o & 1) * 16));
            col[rp[d4.y] + ((old >> ((o & 1) * 16)) & 0xFFFF)] = s4.y;
        }
        o = (unsigned)(d4.z - base);
        if (o < CHUNK_SZ) {
            uint32 old = atomicAdd(&cnt[o >> 1], 1u << ((o & 1) * 16));
            col[rp[d4.z] + ((old >> ((o & 1) * 16)) & 0xFFFF)] = s4.z;
        }
        o = (unsigned)(d4.w - base);
        if (o < CHUNK_SZ) {
            uint32 old = atomicAdd(&cnt[o >> 1], 1u << ((o & 1) * 16));
            col[rp[d4.w] + ((old >> ((o & 1) * 16)) & 0xFFFF)] = s4.w;
        }
    }
    if (slice == NSLICE - 1 && tid == 0) {
        for (int i = nE4 * 4; i < E; ++i) {
            unsigned o = (unsigned)(dst[i] - base);
            if (o < CHUNK_SZ) {
                uint32 old = atomicAdd(&cnt[o >> 1], 1u << ((o & 1) * 16));
                col[rp[dst[i]] + ((old >> ((o & 1) * 16)) & 0xFFFF)] = src[i];
            }
        }
    }
}

// ======================= fused SpMM (shfl-broadcast cols) -> LDS -> GEMM -> bf16 =======================
template <int JOUT>
__global__ __launch_bounds__(256) void k_spmm_gemm(
    const unsigned short* __restrict__ T, const int* __restrict__ rp,
    const int* __restrict__ col, const float* __restrict__ ns,
    const float* __restrict__ nd, const float* __restrict__ bias,
    const float* __restrict__ W, unsigned short* __restrict__ out, int N) {
    __shared__ float Ms[32][132];
    const int n0 = blockIdx.x * 32;
    const int g = threadIdx.x >> 5;
    const int lane = threadIdx.x & 31;
    const uint2* T2 = (const uint2*)T;
    float4 bv = ((const float4*)bias)[lane];
#pragma unroll 1
    for (int rr = 0; rr < 4; ++rr) {
        int row = n0 + g * 4 + rr;
        if (row < N) {
            int s = rp[row], e = rp[row + 1];
            float4 a0 = make_float4(0.f,0.f,0.f,0.f), a1 = a0;
            for (int i = s; i < e; i += 32) {
                int cnt = e - i; if (cnt > 32) cnt = 32;
                int cvec = col[i + (lane < cnt ? lane : cnt - 1)];
                int j = 0;
                for (; j + 7 < cnt; j += 8) {
                    int c0 = __shfl(cvec, j+0, 32), c1 = __shfl(cvec, j+1, 32);
                    int c2 = __shfl(cvec, j+2, 32), c3 = __shfl(cvec, j+3, 32);
                    int c4 = __shfl(cvec, j+4, 32), c5 = __shfl(cvec, j+5, 32);
                    int c6 = __shfl(cvec, j+6, 32), c7 = __shfl(cvec, j+7, 32);
                    uint2 q0 = T2[(size_t)c0 * 32 + lane];
                    uint2 q1 = T2[(size_t)c1 * 32 + lane];
                    uint2 q2 = T2[(size_t)c2 * 32 + lane];
                    uint2 q3 = T2[(size_t)c3 * 32 + lane];
                    uint2 q4 = T2[(size_t)c4 * 32 + lane];
                    uint2 q5 = T2[(size_t)c5 * 32 + lane];
                    uint2 q6 = T2[(size_t)c6 * 32 + lane];
                    uint2 q7 = T2[(size_t)c7 * 32 + lane];
                    acc2(a0, q0); acc2(a1, q1); acc2(a0, q2); acc2(a1, q3);
                    acc2(a0, q4); acc2(a1, q5); acc2(a0, q6); acc2(a1, q7);
                }
                for (; j < cnt; ++j) {
                    int c = __shfl(cvec, j, 32);
                    acc2(a0, T2[(size_t)c * 32 + lane]);
                }
            }
            float4 t;
            t.x = a0.x + a1.x; t.y = a0.y + a1.y;
            t.z = a0.z + a1.z; t.w = a0.w + a1.w;
            float sd = nd[row], sr = ns[row];
            t.x = fmaxf(fmaf(t.x, sd, bv.x), 0.f) * sr;
            t.y = fmaxf(fmaf(t.y, sd, bv.y), 0.f) * sr;
            t.z = fmaxf(fmaf(t.z, sd, bv.z), 0.f) * sr;
            t.w = fmaxf(fmaf(t.w, sd, bv.w), 0.f) * sr;
            *(float4*)&Ms[row - n0][lane * 4] = t;
        }
    }
    __syncthreads();
    const float4* W4 = (const float4*)W;
    if (JOUT == 128) {
        const int tx = threadIdx.x & 31;
        const int ty = threadIdx.x >> 5;
        float acc[4][4] = {};
#pragma unroll 4
        for (int k = 0; k < 128; ++k) {
            float4 wv = W4[(size_t)k * 32 + tx];
#pragma unroll
            for (int i = 0; i < 4; ++i) {
                float m = Ms[ty * 4 + i][k];
                acc[i][0] += m * wv.x; acc[i][1] += m * wv.y;
                acc[i][2] += m * wv.z; acc[i][3] += m * wv.w;
            }
        }
#pragma unroll
        for (int i = 0; i < 4; ++i) {
            int n = n0 + ty * 4 + i;
            if (n < N) {
                ushort4 o;
                o.x = f2bf(acc[i][0]); o.y = f2bf(acc[i][1]);
                o.z = f2bf(acc[i][2]); o.w = f2bf(acc[i][3]);
                *(ushort4*)&out[(size_t)n * 128 + tx * 4] = o;
            }
        }
    } else {
        const int tx = threadIdx.x & 15;
        const int ty = threadIdx.x >> 4;
        float acc[2][4] = {};
#pragma unroll 4
        for (int k = 0; k < 128; ++k) {
            float4 wv = W4[(size_t)k * 16 + tx];
#pragma unroll
            for (int i = 0; i < 2; ++i) {
                float m = Ms[ty * 2 + i][k];
                acc[i][0] += m * wv.x; acc[i][1] += m * wv.y;
                acc[i][2] += m * wv.z; acc[i][3] += m * wv.w;
            }
        }
#pragma unroll
        for (int i = 0; i < 2; ++i) {
            int n = n0 + ty * 2 + i;
            if (n < N) {
                ushort4 o;
                o.x = f2bf(acc[i][0]); o.y = f2bf(acc[i][1]);
                o.z = f2bf(acc[i][2]); o.w = f2bf(acc[i][3]);
                *(ushort4*)&out[(size_t)n * 64 + tx * 4] = o;
            }
        }
    }
}

// ======================= layer-3: bf16 agg (64-dim) + bias + log_softmax =======================
__global__ __launch_bounds__(256) void k_agg64_lsm(
    const unsigned short* __restrict__ Y, const int* __restrict__ rp,
    const int* __restrict__ col, const float* __restrict__ nd,
    const float* __restrict__ b3, float* __restrict__ out, int N) {
    int row = blockIdx.x * 8 + (threadIdx.x >> 5);
    if (row >= N) return;
    int lane = threadIdx.x & 31;
    const uint32* Y2 = (const uint32*)Y;
    int s = rp[row], e = rp[row + 1];
    float lo0 = 0.f, hi0 = 0.f, lo1 = 0.f, hi1 = 0.f;
    for (int i = s; i < e; i += 32) {
        int cnt = e - i; if (cnt > 32) cnt = 32;
        int cvec = col[i + (lane < cnt ? lane : cnt - 1)];
        int j = 0;
        for (; j + 7 < cnt; j += 8) {
            int c0 = __shfl(cvec, j+0, 32), c1 = __shfl(cvec, j+1, 32);
            int c2 = __shfl(cvec, j+2, 32), c3 = __shfl(cvec, j+3, 32);
            int c4 = __shfl(cvec, j+4, 32), c5 = __shfl(cvec, j+5, 32);
            int c6 = __shfl(cvec, j+6, 32), c7 = __shfl(cvec, j+7, 32);
            uint32 q0 = Y2[(size_t)c0 * 32 + lane];
            uint32 q1 = Y2[(size_t)c1 * 32 + lane];
            uint32 q2 = Y2[(size_t)c2 * 32 + lane];
            uint32 q3 = Y2[(size_t)c3 * 32 + lane];
            uint32 q4 = Y2[(size_t)c4 * 32 + lane];
            uint32 q5 = Y2[(size_t)c5 * 32 + lane];
            uint32 q6 = Y2[(size_t)c6 * 32 + lane];
            uint32 q7 = Y2[(size_t)c7 * 32 + lane];
            lo0 += bf_lo(q0); hi0 += bf_hi(q0);
            lo1 += bf_lo(q1); hi1 += bf_hi(q1);
            lo0 += bf_lo(q2); hi0 += bf_hi(q2);
            lo1 += bf_lo(q3); hi1 += bf_hi(q3);
            lo0 += bf_lo(q4); hi0 += bf_hi(q4);
            lo1 += bf_lo(q5); hi1 += bf_hi(q5);
            lo0 += bf_lo(q6); hi0 += bf_hi(q6);
            lo1 += bf_lo(q7); hi1 += bf_hi(q7);
        }
        for (; j < cnt; ++j) {
            int c = __shfl(cvec, j, 32);
            uint32 q = Y2[(size_t)c * 32 + lane];
            lo0 += bf_lo(q); hi0 += bf_hi(q);
        }
    }
    float sd = nd[row];
    float2 bb = ((const float2*)b3)[lane];
    float v0 = (lo0 + lo1) * sd + bb.x;
    float v1 = (hi0 + hi1) * sd + bb.y;
    float m = fmaxf(v0, v1);
#pragma unroll
    for (int o = 16; o; o >>= 1) m = fmaxf(m, __shfl_xor(m, o, 32));
    float ex = expf(v0 - m) + expf(v1 - m);
#pragma unroll
    for (int o = 16; o; o >>= 1) ex += __shfl_xor(ex, o, 32);
    float ls = m + logf(ex);
    ((float2*)out)[(size_t)row * 32 + lane] = make_float2(v0 - ls, v1 - ls);
}

// ======================= launch =======================
extern "C" void kernel_launch(void* const* d_in, const int* in_sizes, int n_in,
                              void* d_out, int out_size, void* d_ws, size_t ws_size,
                              hipStream_t stream) {
    const float* features = (const float*)d_in[0];
    const int*   src      = (const int*)d_in[1];
    const int*   dst      = (const int*)d_in[2];
    const float* W1       = (const float*)d_in[3];
    const float* b1       = (const float*)d_in[4];
    const float* W2       = (const float*)d_in[5];
    const float* b2       = (const float*)d_in[6];
    const float* W3       = (const float*)d_in[7];
    const float* b3       = (const float*)d_in[8];
    float* out = (float*)d_out;

    const int N = in_sizes[0] / D;   // 100000
    const int E = in_sizes[1];       // 1600000

    const int NCHUNK = (N + CHUNK_SZ - 1) >> CHUNK_BITS;   // 7
    const int NH = NCHUNK * NSLICE;                        // 448

    char* p = (char*)d_ws;
    unsigned short* A = (unsigned short*)p; p += (size_t)N * D * sizeof(unsigned short);
    unsigned short* B = (unsigned short*)p; p += (size_t)N * D * sizeof(unsigned short);
    int* col    = (int*)p;   p += (size_t)E * sizeof(int);
    int* rp     = (int*)p;   p += ((size_t)N + 4) * sizeof(int);
    int* degi   = (int*)p;   p += (size_t)N * sizeof(int);
    float* ns   = (float*)p; p += (size_t)N * sizeof(float);
    float* nd   = (float*)p; p += (size_t)N * sizeof(float);
    int* bsum   = (int*)p;   p += 4096 * sizeof(int);
    uint32* histS = (uint32*)p; p += (size_t)NH * HWORDS * sizeof(uint32);
    uint32* histD = (uint32*)p; p += (size_t)NH * HWORDS * sizeof(uint32);

    const int gN  = (N + 255) / 256;          // 391 (<512 for bsum scan)
    const int NBg = (N + 63) / 64;            // 1563 T1-GEMM blocks
    const int periods = 2 * NH;               // 896 hist blocks
    const int gemmPer = (NBg + periods - 1) / periods;   // 2
    const int G1 = periods * (1 + gemmPer);              // 2688

    // K1: [dst-hist | src-hist | T1 = F @ W1] — zero fabric atomics
    k_hist_gemm1<<<G1, 256, 0, stream>>>(src, dst, E, NH, NBg, gemmPer,
                                         histS, histD, features, W1, B, N);
    // merge: degrees + norms; histD -> per-slice prefix table (in place)
    k_merge_norms<<<(NCHUNK * HWORDS + 255) / 256, 256, 0, stream>>>(
        histS, histD, degi, ns, nd, N, NCHUNK);
    k_scan_block<<<gN, 256, 0, stream>>>(degi, rp, bsum, N);
    k_scan_bsum<<<1, 512, 0, stream>>>(bsum, gN);
    k_scan_add<<<(N + 1 + 255) / 256, 256, 0, stream>>>(rp, bsum, N, E);
    // fold ns into T1 (spmm layers become pure adds)
    k_rescale<<<(N * 32 + 255) / 256, 256, 0, stream>>>(B, ns, N);
    // CSR build via LDS-seeded rank counters
    k_rank_scatter<<<NH, 256, 0, stream>>>(src, dst, E, histD, rp, col);

    const int NBn32 = (N + 31) / 32;
    // boundary 1->2: h1s = relu(nd*agg(T1')+b1)*ns ; T2 = h1s @ W2   (B -> A)
    k_spmm_gemm<128><<<NBn32, 256, 0, stream>>>(B, rp, col, ns, nd, b1, W2, A, N);
    // boundary 2->3: h2s = relu(nd*agg(T2)+b2)*ns ; T3 = h2s @ W3    (A -> B)
    k_spmm_gemm<64><<<NBn32, 256, 0, stream>>>(A, rp, col, ns, nd, b2, W3, B, N);
    // final: out = log_softmax(nd*agg64(T3) + b3)
    k_agg64_lsm<<<(N + 7) / 8, 256, 0, stream>>>(B, rp, col, nd, b3, out, N);
}